// Round 1
// baseline (290.137 us; speedup 1.0000x reference)
//
#include <hip/hip_runtime.h>
#include <math.h>

// LinearAttention B=4, S=2048, D=1024 — bf16 MFMA; ALL big GEMMs on 256² 8-phase.
//   qp = softmax(q@Wq^T+bq, axis=-1); kp = softmax(..., axis=-2)/32; vp = softmax(..., axis=-2)
//   attn = qp@kp^T (fp32 out + bf16 ws); out = attn@vp (fp32)
// All GEMMs TN (C[M,N] = A[M,K]·B[N,K]^T), bf16 operands via global_load_lds.
//
// Workspace map (u16 elems; footprint identical to previous session):
//   R0 [0,        8388608): qE  (exp'd q logits -> qp bf16)
//   R1 [8388608, 16777216): kE
//   R2 [16777216,25165824): Wqb@+0, Wkb@+1M, Wvb@+2M (dead after proj)
//   R3 [25165824,33554432): qb (dead after proj) -> vpT [4,1024,2048]
//   R4 [33554432,50331648): kb@+0, vb@+8.4M (dead after proj) -> attnB bf16
//   tail @ 50331648 (floats): kpart, vpart, kinv, vinv, biasCat[3][1024]
//   vE lives in d_out's attn region as u16 scratch (dead before attn GEMM writes it).

typedef float  f32x4  __attribute__((ext_vector_type(4)));
typedef __bf16 bf16x8 __attribute__((ext_vector_type(8)));
typedef int    i32x4  __attribute__((ext_vector_type(4)));
typedef unsigned short u16;

__device__ __forceinline__ float b2f(u16 u) {
    unsigned int i = ((unsigned int)u) << 16; float f;
    __builtin_memcpy(&f, &i, 4); return f;
}
__device__ __forceinline__ u16 f2b(float f) {  // round-to-nearest-even
    unsigned int i; __builtin_memcpy(&i, &f, 4);
    i += 0x7FFFu + ((i >> 16) & 1u);
    return (u16)(i >> 16);
}

// ---- fp32 -> bf16 bulk convert ---------------------------------------------
__global__ __launch_bounds__(256) void cvt_f2b4(const float4* __restrict__ s,
                                                ushort4* __restrict__ d, int n4)
{
    int i = blockIdx.x * 256 + threadIdx.x;
    if (i < n4) {
        float4 v = s[i];
        ushort4 o;
        o.x = f2b(v.x); o.y = f2b(v.y); o.z = f2b(v.z); o.w = f2b(v.w);
        d[i] = o;
    }
}

// ===========================================================================
// 256x256 8-phase TN GEMM (T2 st_16x32 swizzle + T3/T4 counted vmcnt + T5).
// BK=64, 512 threads = 8 waves (2 Mx4 N), per-wave 128x64 = acc[8][4] f32x4.
// LDS 128 KiB: A[2buf][2half][128][64] | B[2buf][2half][128][64] bf16.
// Schedule per K-tile T (cur=T&1): boundary {vmcnt(4); barrier}, then
//  P1: read A-h0,B-g0 | stage B1(T+1)->nxt | bar | lgkm0 | prio 16xMFMA | bar
//  P2: read B-g1      | stage A1(T+1)->nxt | bar | lgkm0 | prio 16xMFMA | bar
//  P3: read A-h1      | stage A0(T+2)->cur | bar | lgkm0 | prio 16xMFMA | bar
//  P4:                | stage B0(T+2)->cur | bar | lgkm0 | prio 16xMFMA | bar
// Race proof: a region staged at phase p was last ds_read >=2 barriers before
// (reads retired at their phase's lgkmcnt(0), ordered by the barrier pair);
// vmcnt(4) at each boundary leaves only the 2 newest halves (needed >=5
// phases later) in flight — all halves of the tile being entered have landed.
//
// EPI: 0 = dual write fp32 + bf16 (attn); 1 = exp(acc+bias)->bf16 (proj,
//      z==2 output redirected to Calt); 2 = fp32 only (out).
// ===========================================================================
template<int EPI>
__global__ __launch_bounds__(512, 2) void gemm256(
    const u16* __restrict__ Ap, const u16* __restrict__ Bp,
    float* __restrict__ C32, u16* __restrict__ C16, u16* __restrict__ Calt,
    const float* __restrict__ bias,
    int N, int K, long long sA, long long sB, long long sC)
{
    __shared__ __align__(16) u16 lds[65536];   // 128 KiB

    const int tid  = threadIdx.x;
    const int lane = tid & 63;
    const int w    = tid >> 6;
    const int wr   = w >> 2, wc = w & 3;       // 2 x 4 waves

    // XCD swizzle within z-plane (tot divisible by 8)
    const int gx  = gridDim.x;
    const int tot = gx * gridDim.y;
    const int lin = blockIdx.y * gx + blockIdx.x;
    const int vlin = (lin & 7) * (tot >> 3) + (lin >> 3);
    const int bx = vlin % gx, by = vlin / gx;
    const int m0 = by * 256, n0 = bx * 256;
    const int z  = blockIdx.z;

    const u16* Ag = Ap + (size_t)z * sA;
    const u16* Bg = Bp + (size_t)z * sB;

    // staging constants: granule c=tid (+512 for 2nd load); logical granule
    // cl = c ^ (bit5(c)<<1)  [st_16x32: flip byte-bit5 when byte-bit9 set]
    const int cl = tid ^ ((tid & 32) >> 4);
    const int lr = cl >> 3;                    // local row 0..63 (2nd: +64)
    const int ce = (cl & 7) * 8;               // col element
    const int arow = m0 + lr;                  // + h*64 ; 2nd load +128
    const int brow = n0 + (lr & 31) + ((lr & 32) << 1);  // + g*32 ; 2nd +128

    // frag-read constants (element offsets within an 8192-elem half)
    const int axr = ((lane >> 2) & 1) << 4;    // read-side swizzle XOR
    const int ar0 = (wr * 64 + (lane & 15)) * 64 + (lane >> 4) * 8;
    const int br0 = (wc * 32 + (lane & 15)) * 64 + (lane >> 4) * 8;

#define GLL16(gsrc, ldsoff)                                                    \
    __builtin_amdgcn_global_load_lds(                                          \
        (__attribute__((address_space(1))) void*)(uintptr_t)(gsrc),            \
        (__attribute__((address_space(3))) void*)&lds[ldsoff], 16, 0, 0)

#define STAGE_A(c, h, T)                                                       \
    do { const u16* _s = Ag + (size_t)(arow + (h) * 64) * K + (T) * 64 + ce;   \
         int _d = (((c) << 1) + (h)) * 8192 + tid * 8;                         \
         GLL16(_s, _d); GLL16(_s + (size_t)128 * K, _d + 4096); } while (0)

#define STAGE_B(c, g, T)                                                       \
    do { const u16* _s = Bg + (size_t)(brow + (g) * 32) * K + (T) * 64 + ce;   \
         int _d = 32768 + (((c) << 1) + (g)) * 8192 + tid * 8;                 \
         GLL16(_s, _d); GLL16(_s + (size_t)128 * K, _d + 4096); } while (0)

#define SBAR asm volatile("s_barrier" ::: "memory")
#define LGKM0 do { asm volatile("s_waitcnt lgkmcnt(0)" ::: "memory");          \
                   __builtin_amdgcn_sched_barrier(0); } while (0)

#define LDA(base)                                                              \
    _Pragma("unroll") for (int mi2 = 0; mi2 < 4; ++mi2)                        \
    _Pragma("unroll") for (int ks = 0; ks < 2; ++ks)                           \
        afr[mi2][ks] = __builtin_bit_cast(bf16x8,                              \
            *(const i32x4*)&lds[(base) + ((ar0 + mi2 * 1024 + ks * 32) ^ axr)]);

#define LDB(dst, base)                                                         \
    _Pragma("unroll") for (int ni2 = 0; ni2 < 2; ++ni2)                        \
    _Pragma("unroll") for (int ks = 0; ks < 2; ++ks)                           \
        dst[ni2][ks] = __builtin_bit_cast(bf16x8,                              \
            *(const i32x4*)&lds[(base) + ((br0 + ni2 * 1024 + ks * 32) ^ axr)]);

#define MFMA_Q(mb, nb, bfrag)                                                  \
    __builtin_amdgcn_s_setprio(1);                                             \
    _Pragma("unroll") for (int mi2 = 0; mi2 < 4; ++mi2)                        \
    _Pragma("unroll") for (int ni2 = 0; ni2 < 2; ++ni2)                        \
    _Pragma("unroll") for (int ks = 0; ks < 2; ++ks)                           \
        acc[(mb) + mi2][(nb) + ni2] = __builtin_amdgcn_mfma_f32_16x16x32_bf16( \
            afr[mi2][ks], bfrag[ni2][ks], acc[(mb) + mi2][(nb) + ni2], 0, 0, 0); \
    __builtin_amdgcn_s_setprio(0)

    f32x4 acc[8][4];
#pragma unroll
    for (int i = 0; i < 8; ++i)
#pragma unroll
        for (int j = 0; j < 4; ++j) acc[i][j] = (f32x4)0.0f;

    bf16x8 afr[4][2], b0f[2][2], b1f[2][2];

    const int nt = K >> 6;

    // prologue: tile0 all 4 halves -> buf0; tile1 A0,B0 -> buf1
    STAGE_A(0, 0, 0); STAGE_B(0, 0, 0);
    STAGE_A(0, 1, 0); STAGE_B(0, 1, 0);
    STAGE_A(1, 0, 1); STAGE_B(1, 0, 1);

    for (int T = 0; T < nt; ++T) {
        const int cur = T & 1, nxt = cur ^ 1;
        const int ab = (cur << 1) * 8192;           // cur A half0 base
        const int bb = 32768 + (cur << 1) * 8192;   // cur B half0 base

        if (T + 1 < nt) asm volatile("s_waitcnt vmcnt(4)" ::: "memory");
        else            asm volatile("s_waitcnt vmcnt(0)" ::: "memory");
        SBAR;
        // ---- P1: quadrant (h0,g0) ----
        LDA(ab); LDB(b0f, bb);
        if (T + 1 < nt) STAGE_B(nxt, 1, T + 1);
        SBAR; LGKM0;
        MFMA_Q(0, 0, b0f);
        SBAR;
        // ---- P2: (h0,g1) ----
        LDB(b1f, bb + 8192);
        if (T + 1 < nt) STAGE_A(nxt, 1, T + 1);
        SBAR; LGKM0;
        MFMA_Q(0, 2, b1f);
        SBAR;
        // ---- P3: (h1,g0) ----
        LDA(ab + 8192);
        if (T + 2 < nt) STAGE_A(cur, 0, T + 2);
        SBAR; LGKM0;
        MFMA_Q(4, 0, b0f);
        SBAR;
        // ---- P4: (h1,g1) ----
        if (T + 2 < nt) STAGE_B(cur, 0, T + 2);
        SBAR; LGKM0;
        MFMA_Q(4, 2, b1f);
        SBAR;
    }

    // epilogue: C row = wr*128 + mi*16 + (lane>>4)*4 + j, col = wc*64 + ni*16 + (lane&15)
    const int cr0 = m0 + wr * 128 + ((lane >> 4) << 2);
    const int cc0 = n0 + wc * 64 + (lane & 15);

    if (EPI == 0) {
        float* Cg = C32 + (size_t)z * sC;
        u16*   Cb = C16 + (size_t)z * sC;
#pragma unroll
        for (int mi = 0; mi < 8; ++mi)
#pragma unroll
            for (int ni = 0; ni < 4; ++ni)
#pragma unroll
                for (int j = 0; j < 4; ++j) {
                    size_t idx = (size_t)(cr0 + mi * 16 + j) * N + cc0 + ni * 16;
                    float vv = acc[mi][ni][j];
                    Cg[idx] = vv;
                    Cb[idx] = f2b(vv);
                }
    } else if (EPI == 1) {
        u16* Cb = (z == 2) ? Calt : (C16 + (size_t)z * sC);
        const float* bz = bias + (size_t)z * 1024;
#pragma unroll
        for (int ni = 0; ni < 4; ++ni) {
            float bv = bz[cc0 + ni * 16];
#pragma unroll
            for (int mi = 0; mi < 8; ++mi)
#pragma unroll
                for (int j = 0; j < 4; ++j) {
                    size_t idx = (size_t)(cr0 + mi * 16 + j) * N + cc0 + ni * 16;
                    Cb[idx] = f2b(__expf(acc[mi][ni][j] + bv));
                }
        }
    } else {
        float* Cg = C32 + (size_t)z * sC;
#pragma unroll
        for (int mi = 0; mi < 8; ++mi)
#pragma unroll
            for (int ni = 0; ni < 4; ++ni)
#pragma unroll
                for (int j = 0; j < 4; ++j) {
                    size_t idx = (size_t)(cr0 + mi * 16 + j) * N + cc0 + ni * 16;
                    Cg[idx] = acc[mi][ni][j];
                }
    }
#undef GLL16
#undef STAGE_A
#undef STAGE_B
#undef SBAR
#undef LGKM0
#undef LDA
#undef LDB
#undef MFMA_Q
}

// ---- row softmax over D=1024, in place on exp'd bf16 ----------------------
__global__ __launch_bounds__(256) void row_softmax_bf16(u16* __restrict__ d)
{
    size_t row = blockIdx.x;
    u16* p = d + row * 1024;
    int t = threadIdx.x;
    ushort4 v = *(ushort4*)&p[t * 4];
    float e0 = b2f(v.x), e1 = b2f(v.y), e2 = b2f(v.z), e3 = b2f(v.w);
    float s = (e0 + e1) + (e2 + e3);
#pragma unroll
    for (int off = 32; off; off >>= 1) s += __shfl_down(s, off);
    __shared__ float red[4];
    if ((t & 63) == 0) red[t >> 6] = s;
    __syncthreads();
    float inv = 1.0f / ((red[0] + red[1]) + (red[2] + red[3]));
    ushort4 o;
    o.x = f2b(e0 * inv); o.y = f2b(e1 * inv); o.z = f2b(e2 * inv); o.w = f2b(e3 * inv);
    *(ushort4*)&p[t * 4] = o;
}

// ---- column-sum partials over s (128-row chunks) --------------------------
__global__ __launch_bounds__(256) void col_partial(const u16* __restrict__ d,
                                                   float* __restrict__ part)
{
    int b = blockIdx.y, c = blockIdx.x, t = threadIdx.x;
    const u16* base = d + ((size_t)b * 2048 + c * 128) * 1024 + t * 4;
    float a0 = 0, a1 = 0, a2 = 0, a3 = 0;
    for (int s = 0; s < 128; ++s) {
        ushort4 v = *(const ushort4*)(base + (size_t)s * 1024);
        a0 += b2f(v.x); a1 += b2f(v.y); a2 += b2f(v.z); a3 += b2f(v.w);
    }
    *(float4*)(part + ((size_t)(b * 16 + c)) * 1024 + t * 4) = make_float4(a0, a1, a2, a3);
}

__global__ __launch_bounds__(256) void col_reduce(const float* __restrict__ part,
                                                  float* __restrict__ inv, float mult)
{
    int idx = blockIdx.x * 256 + threadIdx.x;  // 0..4095 over (b,e)
    int b = idx >> 10, e = idx & 1023;
    float s = 0;
    for (int c = 0; c < 16; ++c) s += part[((size_t)(b * 16 + c)) * 1024 + e];
    inv[idx] = mult / s;
}

// ---- kp: in-place normalize ------------------------------------------------
__global__ __launch_bounds__(256) void col_norm(u16* __restrict__ d,
                                                const float* __restrict__ inv)
{
    int b = blockIdx.y, s = blockIdx.x, t = threadIdx.x;
    u16* p = d + ((size_t)b * 2048 + s) * 1024 + t * 4;
    float4 iv = *(const float4*)(inv + b * 1024 + t * 4);
    ushort4 v = *(ushort4*)p;
    v.x = f2b(b2f(v.x) * iv.x); v.y = f2b(b2f(v.y) * iv.y);
    v.z = f2b(b2f(v.z) * iv.z); v.w = f2b(b2f(v.w) * iv.w);
    *(ushort4*)p = v;
}

// ---- vp: normalize + transpose to vpT[b][e][s] -----------------------------
__global__ __launch_bounds__(256) void transpose_norm(const u16* __restrict__ d,
                                                      const float* __restrict__ inv,
                                                      u16* __restrict__ o)
{
    __shared__ __align__(16) u16 tile[64][68];
    int b = blockIdx.z, s0 = blockIdx.x * 64, e0 = blockIdx.y * 64, t = threadIdx.x;
    int lr = t >> 4, lc = (t & 15) * 4;
#pragma unroll
    for (int i = 0; i < 4; ++i) {
        int sr = i * 16 + lr;
        ushort4 v = *(const ushort4*)(d + ((size_t)b * 2048 + s0 + sr) * 1024 + e0 + lc);
        tile[sr][lc] = v.x; tile[sr][lc + 1] = v.y;
        tile[sr][lc + 2] = v.z; tile[sr][lc + 3] = v.w;
    }
    __syncthreads();
#pragma unroll
    for (int i = 0; i < 4; ++i) {
        int er = i * 16 + lr;
        float iv = inv[b * 1024 + e0 + er];
        ushort4 v;
        v.x = f2b(b2f(tile[lc + 0][er]) * iv);
        v.y = f2b(b2f(tile[lc + 1][er]) * iv);
        v.z = f2b(b2f(tile[lc + 2][er]) * iv);
        v.w = f2b(b2f(tile[lc + 3][er]) * iv);
        *(ushort4*)(o + ((size_t)b * 1024 + e0 + er) * 2048 + s0 + lc) = v;
    }
}

extern "C" void kernel_launch(void* const* d_in, const int* in_sizes, int n_in,
                              void* d_out, int out_size, void* d_ws, size_t ws_size,
                              hipStream_t stream)
{
    const float* q  = (const float*)d_in[0];
    const float* k  = (const float*)d_in[1];
    const float* v  = (const float*)d_in[2];
    const float* Wq = (const float*)d_in[3];
    const float* bq = (const float*)d_in[4];
    const float* Wk = (const float*)d_in[5];
    const float* bk = (const float*)d_in[6];
    const float* Wv = (const float*)d_in[7];
    const float* bv = (const float*)d_in[8];

    float* out  = (float*)d_out;          // [4,2048,1024] fp32
    float* attn = out + 8388608;          // [4,2048,2048] fp32

    u16* wsU = (u16*)d_ws;
    u16* qE   = wsU;                      // R0: exp'd q logits -> qp
    u16* kE   = wsU + 8388608;            // R1: exp'd k logits -> kp
    u16* Wb   = wsU + 16777216;           // R2: Wqb|Wkb|Wvb (stride 1M)
    u16* qb   = wsU + 25165824;           // R3: q bf16 (dead after proj)
    u16* kb   = wsU + 33554432;           // R4: k bf16 (dead after proj)
    u16* vb   = wsU + 41943040;           // R4+8.4M: v bf16 (dead after proj)
    u16* vpT  = wsU + 25165824;           // R3 after proj: vpT [4,1024,2048]
    u16* attnB = wsU + 33554432;          // R4 after proj: attn bf16
    u16* vE   = (u16*)attn;               // d_out attn region as scratch (dead
                                          // before the attn GEMM overwrites it)

    float* tail  = (float*)(wsU + 50331648);
    float* kpart = tail;                  // [4,16,1024]
    float* vpart = tail + 65536;
    float* kinv  = tail + 131072;         // [4,1024]
    float* vinv  = tail + 135168;
    float* biasCat = tail + 139264;       // [3,1024] bq|bk|bv

    dim3 blk(256);
    const long long SD = 2048LL * 1024, SS = 2048LL * 2048, DS = 1024LL * 2048;

    // ---- convert inputs + weights to bf16; gather biases ----
    cvt_f2b4<<<dim3(8192), blk, 0, stream>>>((const float4*)q, (ushort4*)qb, 2097152);
    cvt_f2b4<<<dim3(8192), blk, 0, stream>>>((const float4*)k, (ushort4*)kb, 2097152);
    cvt_f2b4<<<dim3(8192), blk, 0, stream>>>((const float4*)v, (ushort4*)vb, 2097152);
    cvt_f2b4<<<dim3(1024), blk, 0, stream>>>((const float4*)Wq, (ushort4*)(Wb), 262144);
    cvt_f2b4<<<dim3(1024), blk, 0, stream>>>((const float4*)Wk, (ushort4*)(Wb + 1048576), 262144);
    cvt_f2b4<<<dim3(1024), blk, 0, stream>>>((const float4*)Wv, (ushort4*)(Wb + 2097152), 262144);
    hipMemcpyAsync(biasCat,        bq, 4096, hipMemcpyDeviceToDevice, stream);
    hipMemcpyAsync(biasCat + 1024, bk, 4096, hipMemcpyDeviceToDevice, stream);
    hipMemcpyAsync(biasCat + 2048, bv, 4096, hipMemcpyDeviceToDevice, stream);

    // ---- batched projections: z=0/1/2 -> qE, kE, vE(scratch) ----
    // A: qb|kb|vb contiguous stride 8388608; B: Wb stride 1048576;
    // C: qE/kE via stride, z==2 redirected to vE scratch.
    gemm256<1><<<dim3(4, 32, 3), dim3(512), 0, stream>>>(
        qb, Wb, nullptr, qE, vE, biasCat,
        1024, 1024, 8388608LL, 1048576LL, 8388608LL);

    // ---- softmax normalizations ----
    row_softmax_bf16<<<dim3(8192), blk, 0, stream>>>(qE);
    col_partial<<<dim3(16, 4), blk, 0, stream>>>(kE, kpart);
    col_partial<<<dim3(16, 4), blk, 0, stream>>>(vE, vpart);
    col_reduce<<<dim3(16), blk, 0, stream>>>(kpart, kinv, 0.03125f);  // 1/sqrt(1024)
    col_reduce<<<dim3(16), blk, 0, stream>>>(vpart, vinv, 1.0f);
    col_norm<<<dim3(2048, 4), blk, 0, stream>>>(kE, kinv);
    transpose_norm<<<dim3(32, 16, 4), blk, 0, stream>>>(vE, vinv, vpT);

    // ---- attn = qp @ kp^T -> fp32 d_out + bf16 ws copy (overwrites vE scratch) ----
    gemm256<0><<<dim3(8, 8, 4), dim3(512), 0, stream>>>(
        qE, kE, attn, attnB, nullptr, nullptr, 2048, 1024, SD, SD, SS);

    // ---- out = attnB @ vpT^T -> fp32 d_out ----
    gemm256<2><<<dim3(4, 8, 4), dim3(512), 0, stream>>>(
        attnB, vpT, out, nullptr, nullptr, nullptr, 1024, 2048, SS, DS, SD);
}

// Round 2
// 288.475 us; speedup vs baseline: 1.0058x; 1.0058x over previous
//
#include <hip/hip_runtime.h>
#include <math.h>

// LinearAttention B=4, S=2048, D=1024 — bf16 MFMA; ALL big GEMMs on 256² 8-phase.
//   qp = softmax(q@Wq^T+bq, axis=-1); kp = softmax(..., axis=-2)/32; vp = softmax(..., axis=-2)
//   attn = qp@kp^T (fp32 out + bf16 ws); out = attn@vp (fp32)
// All GEMMs TN (C[M,N] = A[M,K]·B[N,K]^T), bf16 operands via global_load_lds.
//
// R2 change: bf16 C-writes (EPI 0/1) now go through LDS (free after K-loop) and
// out as coalesced dwordx4 — the old 2-byte scattered stores (128/thread) were
// ~half the block time at nt=16 (WRITE_SIZE showed 1.6x RMW inflation).
//
// Workspace map (u16 elems):
//   R0 [0,        8388608): qE  (exp'd q logits -> qp bf16)
//   R1 [8388608, 16777216): kE
//   R2 [16777216,25165824): Wqb@+0, Wkb@+1M, Wvb@+2M (dead after proj)
//   R3 [25165824,33554432): qb (dead after proj) -> vpT [4,1024,2048]
//   R4 [33554432,50331648): kb@+0, vb@+8.4M (dead after proj) -> attnB bf16
//   tail @ 50331648 (floats): kpart, vpart, kinv, vinv, biasCat[3][1024]
//   vE lives in d_out's attn region as u16 scratch (dead before attn GEMM writes it).

typedef float  f32x4  __attribute__((ext_vector_type(4)));
typedef __bf16 bf16x8 __attribute__((ext_vector_type(8)));
typedef int    i32x4  __attribute__((ext_vector_type(4)));
typedef unsigned short u16;

__device__ __forceinline__ float b2f(u16 u) {
    unsigned int i = ((unsigned int)u) << 16; float f;
    __builtin_memcpy(&f, &i, 4); return f;
}
__device__ __forceinline__ u16 f2b(float f) {  // round-to-nearest-even
    unsigned int i; __builtin_memcpy(&i, &f, 4);
    i += 0x7FFFu + ((i >> 16) & 1u);
    return (u16)(i >> 16);
}

// ---- fp32 -> bf16 bulk convert ---------------------------------------------
__global__ __launch_bounds__(256) void cvt_f2b4(const float4* __restrict__ s,
                                                ushort4* __restrict__ d, int n4)
{
    int i = blockIdx.x * 256 + threadIdx.x;
    if (i < n4) {
        float4 v = s[i];
        ushort4 o;
        o.x = f2b(v.x); o.y = f2b(v.y); o.z = f2b(v.z); o.w = f2b(v.w);
        d[i] = o;
    }
}

// ===========================================================================
// 256x256 8-phase TN GEMM (T2 st_16x32 swizzle + T3/T4 counted vmcnt + T5).
// BK=64, 512 threads = 8 waves (2 Mx4 N), per-wave 128x64 = acc[8][4] f32x4.
// LDS 128 KiB: A[2buf][2half][128][64] | B[2buf][2half][128][64] bf16.
// Schedule per K-tile T (cur=T&1): boundary {vmcnt(4); barrier}, then
//  P1: read A-h0,B-g0 | stage B1(T+1)->nxt | bar | lgkm0 | prio 16xMFMA | bar
//  P2: read B-g1      | stage A1(T+1)->nxt | bar | lgkm0 | prio 16xMFMA | bar
//  P3: read A-h1      | stage A0(T+2)->cur | bar | lgkm0 | prio 16xMFMA | bar
//  P4:                | stage B0(T+2)->cur | bar | lgkm0 | prio 16xMFMA | bar
// Race proof: a region staged at phase p was last ds_read >=2 barriers before
// (reads retired at their phase's lgkmcnt(0), ordered by the barrier pair);
// vmcnt(4) at each boundary leaves only the 2 newest halves (needed >=5
// phases later) in flight — all halves of the tile being entered have landed.
// After the loop no staging is outstanding (vmcnt(0) at last boundary, no
// STAGE in final tile) -> __syncthreads() then LDS is reusable for epilogue.
//
// EPI: 0 = dual write fp32 (direct) + bf16 (LDS-coalesced) (attn);
//      1 = exp(acc+bias)->bf16 LDS-coalesced (proj, z==2 -> Calt);
//      2 = fp32 only, direct (out).
// ===========================================================================
template<int EPI>
__global__ __launch_bounds__(512, 2) void gemm256(
    const u16* __restrict__ Ap, const u16* __restrict__ Bp,
    float* __restrict__ C32, u16* __restrict__ C16, u16* __restrict__ Calt,
    const float* __restrict__ bias,
    int N, int K, long long sA, long long sB, long long sC)
{
    __shared__ __align__(16) u16 lds[65536];   // 128 KiB

    const int tid  = threadIdx.x;
    const int lane = tid & 63;
    const int w    = tid >> 6;
    const int wr   = w >> 2, wc = w & 3;       // 2 x 4 waves

    // XCD swizzle within z-plane (tot divisible by 8)
    const int gx  = gridDim.x;
    const int tot = gx * gridDim.y;
    const int lin = blockIdx.y * gx + blockIdx.x;
    const int vlin = (lin & 7) * (tot >> 3) + (lin >> 3);
    const int bx = vlin % gx, by = vlin / gx;
    const int m0 = by * 256, n0 = bx * 256;
    const int z  = blockIdx.z;

    const u16* Ag = Ap + (size_t)z * sA;
    const u16* Bg = Bp + (size_t)z * sB;

    // staging constants: granule c=tid (+512 for 2nd load); logical granule
    // cl = c ^ (bit5(c)<<1)  [st_16x32: flip byte-bit5 when byte-bit9 set]
    const int cl = tid ^ ((tid & 32) >> 4);
    const int lr = cl >> 3;                    // local row 0..63 (2nd: +64)
    const int ce = (cl & 7) * 8;               // col element
    const int arow = m0 + lr;                  // + h*64 ; 2nd load +128
    const int brow = n0 + (lr & 31) + ((lr & 32) << 1);  // + g*32 ; 2nd +128

    // frag-read constants (element offsets within an 8192-elem half)
    const int axr = ((lane >> 2) & 1) << 4;    // read-side swizzle XOR
    const int ar0 = (wr * 64 + (lane & 15)) * 64 + (lane >> 4) * 8;
    const int br0 = (wc * 32 + (lane & 15)) * 64 + (lane >> 4) * 8;

#define GLL16(gsrc, ldsoff)                                                    \
    __builtin_amdgcn_global_load_lds(                                          \
        (__attribute__((address_space(1))) void*)(uintptr_t)(gsrc),            \
        (__attribute__((address_space(3))) void*)&lds[ldsoff], 16, 0, 0)

#define STAGE_A(c, h, T)                                                       \
    do { const u16* _s = Ag + (size_t)(arow + (h) * 64) * K + (T) * 64 + ce;   \
         int _d = (((c) << 1) + (h)) * 8192 + tid * 8;                         \
         GLL16(_s, _d); GLL16(_s + (size_t)128 * K, _d + 4096); } while (0)

#define STAGE_B(c, g, T)                                                       \
    do { const u16* _s = Bg + (size_t)(brow + (g) * 32) * K + (T) * 64 + ce;   \
         int _d = 32768 + (((c) << 1) + (g)) * 8192 + tid * 8;                 \
         GLL16(_s, _d); GLL16(_s + (size_t)128 * K, _d + 4096); } while (0)

#define SBAR asm volatile("s_barrier" ::: "memory")
#define LGKM0 do { asm volatile("s_waitcnt lgkmcnt(0)" ::: "memory");          \
                   __builtin_amdgcn_sched_barrier(0); } while (0)

#define LDA(base)                                                              \
    _Pragma("unroll") for (int mi2 = 0; mi2 < 4; ++mi2)                        \
    _Pragma("unroll") for (int ks = 0; ks < 2; ++ks)                           \
        afr[mi2][ks] = __builtin_bit_cast(bf16x8,                              \
            *(const i32x4*)&lds[(base) + ((ar0 + mi2 * 1024 + ks * 32) ^ axr)]);

#define LDB(dst, base)                                                         \
    _Pragma("unroll") for (int ni2 = 0; ni2 < 2; ++ni2)                        \
    _Pragma("unroll") for (int ks = 0; ks < 2; ++ks)                           \
        dst[ni2][ks] = __builtin_bit_cast(bf16x8,                              \
            *(const i32x4*)&lds[(base) + ((br0 + ni2 * 1024 + ks * 32) ^ axr)]);

#define MFMA_Q(mb, nb, bfrag)                                                  \
    __builtin_amdgcn_s_setprio(1);                                             \
    _Pragma("unroll") for (int mi2 = 0; mi2 < 4; ++mi2)                        \
    _Pragma("unroll") for (int ni2 = 0; ni2 < 2; ++ni2)                        \
    _Pragma("unroll") for (int ks = 0; ks < 2; ++ks)                           \
        acc[(mb) + mi2][(nb) + ni2] = __builtin_amdgcn_mfma_f32_16x16x32_bf16( \
            afr[mi2][ks], bfrag[ni2][ks], acc[(mb) + mi2][(nb) + ni2], 0, 0, 0); \
    __builtin_amdgcn_s_setprio(0)

    f32x4 acc[8][4];
#pragma unroll
    for (int i = 0; i < 8; ++i)
#pragma unroll
        for (int j = 0; j < 4; ++j) acc[i][j] = (f32x4)0.0f;

    bf16x8 afr[4][2], b0f[2][2], b1f[2][2];

    const int nt = K >> 6;

    // prologue: tile0 all 4 halves -> buf0; tile1 A0,B0 -> buf1
    STAGE_A(0, 0, 0); STAGE_B(0, 0, 0);
    STAGE_A(0, 1, 0); STAGE_B(0, 1, 0);
    STAGE_A(1, 0, 1); STAGE_B(1, 0, 1);

    for (int T = 0; T < nt; ++T) {
        const int cur = T & 1, nxt = cur ^ 1;
        const int ab = (cur << 1) * 8192;           // cur A half0 base
        const int bb = 32768 + (cur << 1) * 8192;   // cur B half0 base

        if (T + 1 < nt) asm volatile("s_waitcnt vmcnt(4)" ::: "memory");
        else            asm volatile("s_waitcnt vmcnt(0)" ::: "memory");
        SBAR;
        // ---- P1: quadrant (h0,g0) ----
        LDA(ab); LDB(b0f, bb);
        if (T + 1 < nt) STAGE_B(nxt, 1, T + 1);
        SBAR; LGKM0;
        MFMA_Q(0, 0, b0f);
        SBAR;
        // ---- P2: (h0,g1) ----
        LDB(b1f, bb + 8192);
        if (T + 1 < nt) STAGE_A(nxt, 1, T + 1);
        SBAR; LGKM0;
        MFMA_Q(0, 2, b1f);
        SBAR;
        // ---- P3: (h1,g0) ----
        LDA(ab + 8192);
        if (T + 2 < nt) STAGE_A(cur, 0, T + 2);
        SBAR; LGKM0;
        MFMA_Q(4, 0, b0f);
        SBAR;
        // ---- P4: (h1,g1) ----
        if (T + 2 < nt) STAGE_B(cur, 0, T + 2);
        SBAR; LGKM0;
        MFMA_Q(4, 2, b1f);
        SBAR;
    }

    // ------------------------------------------------------------------
    // Epilogue. C row = wr*128 + mi*16 + (lane>>4)*4 + j,
    //           col = wc*64 + ni*16 + (lane&15).
    // bf16 outputs go through LDS [128][264] u16 (stride 264: 16B-aligned
    // b128 reads, ~2-way banks) in two row-half passes, emitted as
    // coalesced dwordx4 (16 rows x 64B contiguous per wave-instruction).
    // ------------------------------------------------------------------
    const int cr0 = m0 + wr * 128 + ((lane >> 4) << 2);
    const int cc0 = n0 + wc * 64 + (lane & 15);

    if (EPI == 2 || EPI == 0) {
        float* Cg = C32 + (size_t)z * sC;
#pragma unroll
        for (int mi = 0; mi < 8; ++mi)
#pragma unroll
            for (int ni = 0; ni < 4; ++ni)
#pragma unroll
                for (int j = 0; j < 4; ++j)
                    Cg[(size_t)(cr0 + mi * 16 + j) * N + cc0 + ni * 16] = acc[mi][ni][j];
    }

    if (EPI == 0 || EPI == 1) {
        u16* sE = lds;                         // [128][264] u16 = 67584 B
        u16* Cb;
        float bv[4];
        if (EPI == 1) {
            Cb = (z == 2) ? Calt : (C16 + (size_t)z * sC);
#pragma unroll
            for (int ni = 0; ni < 4; ++ni) bv[ni] = bias[(size_t)z * 1024 + cc0 + ni * 16];
        } else {
            Cb = C16 + (size_t)z * sC;
        }
        const int wrow0 = ((lane >> 4) << 2);                 // + mi*16 + j
        const int wcol0 = wc * 64 + (lane & 15);              // + ni*16
        const int rr = tid >> 2;                              // read row 0..127
        const int c0 = (tid & 3) * 8;                         // + i*32

        __syncthreads();                       // LDS free (see race proof)
#pragma unroll
        for (int p = 0; p < 2; ++p) {
            if (wr == p) {
#pragma unroll
                for (int mi = 0; mi < 8; ++mi)
#pragma unroll
                    for (int ni = 0; ni < 4; ++ni)
#pragma unroll
                        for (int j = 0; j < 4; ++j) {
                            float vv = acc[mi][ni][j];
                            if (EPI == 1) vv = __expf(vv + bv[ni]);
                            sE[(wrow0 + mi * 16 + j) * 264 + wcol0 + ni * 16] = f2b(vv);
                        }
            }
            __syncthreads();
#pragma unroll
            for (int i = 0; i < 8; ++i) {
                i32x4 vv = *(const i32x4*)&sE[rr * 264 + c0 + i * 32];
                *(i32x4*)&Cb[(size_t)(m0 + p * 128 + rr) * N + n0 + c0 + i * 32] = vv;
            }
            if (p == 0) __syncthreads();       // before pass-1 overwrite
        }
    }
#undef GLL16
#undef STAGE_A
#undef STAGE_B
#undef SBAR
#undef LGKM0
#undef LDA
#undef LDB
#undef MFMA_Q
}

// ---- row softmax over D=1024, in place on exp'd bf16 ----------------------
__global__ __launch_bounds__(256) void row_softmax_bf16(u16* __restrict__ d)
{
    size_t row = blockIdx.x;
    u16* p = d + row * 1024;
    int t = threadIdx.x;
    ushort4 v = *(ushort4*)&p[t * 4];
    float e0 = b2f(v.x), e1 = b2f(v.y), e2 = b2f(v.z), e3 = b2f(v.w);
    float s = (e0 + e1) + (e2 + e3);
#pragma unroll
    for (int off = 32; off; off >>= 1) s += __shfl_down(s, off);
    __shared__ float red[4];
    if ((t & 63) == 0) red[t >> 6] = s;
    __syncthreads();
    float inv = 1.0f / ((red[0] + red[1]) + (red[2] + red[3]));
    ushort4 o;
    o.x = f2b(e0 * inv); o.y = f2b(e1 * inv); o.z = f2b(e2 * inv); o.w = f2b(e3 * inv);
    *(ushort4*)&p[t * 4] = o;
}

// ---- column-sum partials over s (128-row chunks) --------------------------
__global__ __launch_bounds__(256) void col_partial(const u16* __restrict__ d,
                                                   float* __restrict__ part)
{
    int b = blockIdx.y, c = blockIdx.x, t = threadIdx.x;
    const u16* base = d + ((size_t)b * 2048 + c * 128) * 1024 + t * 4;
    float a0 = 0, a1 = 0, a2 = 0, a3 = 0;
    for (int s = 0; s < 128; ++s) {
        ushort4 v = *(const ushort4*)(base + (size_t)s * 1024);
        a0 += b2f(v.x); a1 += b2f(v.y); a2 += b2f(v.z); a3 += b2f(v.w);
    }
    *(float4*)(part + ((size_t)(b * 16 + c)) * 1024 + t * 4) = make_float4(a0, a1, a2, a3);
}

__global__ __launch_bounds__(256) void col_reduce(const float* __restrict__ part,
                                                  float* __restrict__ inv, float mult)
{
    int idx = blockIdx.x * 256 + threadIdx.x;  // 0..4095 over (b,e)
    int b = idx >> 10, e = idx & 1023;
    float s = 0;
    for (int c = 0; c < 16; ++c) s += part[((size_t)(b * 16 + c)) * 1024 + e];
    inv[idx] = mult / s;
}

// ---- kp: in-place normalize ------------------------------------------------
__global__ __launch_bounds__(256) void col_norm(u16* __restrict__ d,
                                                const float* __restrict__ inv)
{
    int b = blockIdx.y, s = blockIdx.x, t = threadIdx.x;
    u16* p = d + ((size_t)b * 2048 + s) * 1024 + t * 4;
    float4 iv = *(const float4*)(inv + b * 1024 + t * 4);
    ushort4 v = *(ushort4*)p;
    v.x = f2b(b2f(v.x) * iv.x); v.y = f2b(b2f(v.y) * iv.y);
    v.z = f2b(b2f(v.z) * iv.z); v.w = f2b(b2f(v.w) * iv.w);
    *(ushort4*)p = v;
}

// ---- vp: normalize + transpose to vpT[b][e][s] -----------------------------
__global__ __launch_bounds__(256) void transpose_norm(const u16* __restrict__ d,
                                                      const float* __restrict__ inv,
                                                      u16* __restrict__ o)
{
    __shared__ __align__(16) u16 tile[64][68];
    int b = blockIdx.z, s0 = blockIdx.x * 64, e0 = blockIdx.y * 64, t = threadIdx.x;
    int lr = t >> 4, lc = (t & 15) * 4;
#pragma unroll
    for (int i = 0; i < 4; ++i) {
        int sr = i * 16 + lr;
        ushort4 v = *(const ushort4*)(d + ((size_t)b * 2048 + s0 + sr) * 1024 + e0 + lc);
        tile[sr][lc] = v.x; tile[sr][lc + 1] = v.y;
        tile[sr][lc + 2] = v.z; tile[sr][lc + 3] = v.w;
    }
    __syncthreads();
#pragma unroll
    for (int i = 0; i < 4; ++i) {
        int er = i * 16 + lr;
        float iv = inv[b * 1024 + e0 + er];
        ushort4 v;
        v.x = f2b(b2f(tile[lc + 0][er]) * iv);
        v.y = f2b(b2f(tile[lc + 1][er]) * iv);
        v.z = f2b(b2f(tile[lc + 2][er]) * iv);
        v.w = f2b(b2f(tile[lc + 3][er]) * iv);
        *(ushort4*)(o + ((size_t)b * 1024 + e0 + er) * 2048 + s0 + lc) = v;
    }
}

extern "C" void kernel_launch(void* const* d_in, const int* in_sizes, int n_in,
                              void* d_out, int out_size, void* d_ws, size_t ws_size,
                              hipStream_t stream)
{
    const float* q  = (const float*)d_in[0];
    const float* k  = (const float*)d_in[1];
    const float* v  = (const float*)d_in[2];
    const float* Wq = (const float*)d_in[3];
    const float* bq = (const float*)d_in[4];
    const float* Wk = (const float*)d_in[5];
    const float* bk = (const float*)d_in[6];
    const float* Wv = (const float*)d_in[7];
    const float* bv = (const float*)d_in[8];

    float* out  = (float*)d_out;          // [4,2048,1024] fp32
    float* attn = out + 8388608;          // [4,2048,2048] fp32

    u16* wsU = (u16*)d_ws;
    u16* qE   = wsU;                      // R0: exp'd q logits -> qp
    u16* kE   = wsU + 8388608;            // R1: exp'd k logits -> kp
    u16* Wb   = wsU + 16777216;           // R2: Wqb|Wkb|Wvb (stride 1M)
    u16* qb   = wsU + 25165824;           // R3: q bf16 (dead after proj)
    u16* kb   = wsU + 33554432;           // R4: k bf16 (dead after proj)
    u16* vb   = wsU + 41943040;           // R4+8.4M: v bf16 (dead after proj)
    u16* vpT  = wsU + 25165824;           // R3 after proj: vpT [4,1024,2048]
    u16* attnB = wsU + 33554432;          // R4 after proj: attn bf16
    u16* vE   = (u16*)attn;               // d_out attn region as scratch (dead
                                          // before the attn GEMM overwrites it)

    float* tail  = (float*)(wsU + 50331648);
    float* kpart = tail;                  // [4,16,1024]
    float* vpart = tail + 65536;
    float* kinv  = tail + 131072;         // [4,1024]
    float* vinv  = tail + 135168;
    float* biasCat = tail + 139264;       // [3,1024] bq|bk|bv

    dim3 blk(256);
    const long long SD = 2048LL * 1024, SS = 2048LL * 2048, DS = 1024LL * 2048;

    // ---- convert inputs + weights to bf16; gather biases ----
    cvt_f2b4<<<dim3(8192), blk, 0, stream>>>((const float4*)q, (ushort4*)qb, 2097152);
    cvt_f2b4<<<dim3(8192), blk, 0, stream>>>((const float4*)k, (ushort4*)kb, 2097152);
    cvt_f2b4<<<dim3(8192), blk, 0, stream>>>((const float4*)v, (ushort4*)vb, 2097152);
    cvt_f2b4<<<dim3(1024), blk, 0, stream>>>((const float4*)Wq, (ushort4*)(Wb), 262144);
    cvt_f2b4<<<dim3(1024), blk, 0, stream>>>((const float4*)Wk, (ushort4*)(Wb + 1048576), 262144);
    cvt_f2b4<<<dim3(1024), blk, 0, stream>>>((const float4*)Wv, (ushort4*)(Wb + 2097152), 262144);
    hipMemcpyAsync(biasCat,        bq, 4096, hipMemcpyDeviceToDevice, stream);
    hipMemcpyAsync(biasCat + 1024, bk, 4096, hipMemcpyDeviceToDevice, stream);
    hipMemcpyAsync(biasCat + 2048, bv, 4096, hipMemcpyDeviceToDevice, stream);

    // ---- batched projections: z=0/1/2 -> qE, kE, vE(scratch) ----
    gemm256<1><<<dim3(4, 32, 3), dim3(512), 0, stream>>>(
        qb, Wb, nullptr, qE, vE, biasCat,
        1024, 1024, 8388608LL, 1048576LL, 8388608LL);

    // ---- softmax normalizations ----
    row_softmax_bf16<<<dim3(8192), blk, 0, stream>>>(qE);
    col_partial<<<dim3(16, 4), blk, 0, stream>>>(kE, kpart);
    col_partial<<<dim3(16, 4), blk, 0, stream>>>(vE, vpart);
    col_reduce<<<dim3(16), blk, 0, stream>>>(kpart, kinv, 0.03125f);  // 1/sqrt(1024)
    col_reduce<<<dim3(16), blk, 0, stream>>>(vpart, vinv, 1.0f);
    col_norm<<<dim3(2048, 4), blk, 0, stream>>>(kE, kinv);
    transpose_norm<<<dim3(32, 16, 4), blk, 0, stream>>>(vE, vinv, vpT);

    // ---- attn = qp @ kp^T -> fp32 d_out + bf16 ws copy ----
    gemm256<0><<<dim3(8, 8, 4), dim3(512), 0, stream>>>(
        qE, kE, attn, attnB, nullptr, nullptr, 2048, 1024, SD, SD, SS);

    // ---- out = attnB @ vpT^T -> fp32 d_out ----
    gemm256<2><<<dim3(4, 8, 4), dim3(512), 0, stream>>>(
        attnB, vpT, out, nullptr, nullptr, nullptr, 1024, 2048, SS, DS, SD);
}

// Round 3
// 245.377 us; speedup vs baseline: 1.1824x; 1.1756x over previous
//
#include <hip/hip_runtime.h>
#include <math.h>

// LinearAttention B=4, S=2048, D=1024 — bf16 MFMA; ALL big GEMMs on the 8-phase
// template. R3: BN-templated tile (256x256 / 256x128) for grid fill:
//   proj: 256x128 tile, grid 8x32x3 = 768 blocks (3 clean rounds)
//   attn: 256x256 tile, grid 8x8x4  = 256 blocks (1 round)
//   out : 256x128 tile, grid 8x8x4  = 256 blocks (1 round; was 128 half-idle)
// Plus small-kernel fusion: 13 launches -> 7.
//
// Workspace map (u16 elems):
//   R0 [0,        8388608): qE  (exp'd q logits -> qp bf16)
//   R1 [8388608, 16777216): kE
//   R2 [16777216,25165824): Wqb@+0, Wkb@+1M, Wvb@+2M (dead after proj)
//   R3 [25165824,33554432): qb (dead after proj) -> vpT [4,1024,2048]
//   R4 [33554432,50331648): kb@+0, vb@+8.4M (dead after proj) -> attnB bf16
//   tail @ 50331648 (floats): kpart, vpart, kinv, vinv, biasCat[3][1024]
//   vE lives in d_out's attn region as u16 scratch (dead before attn GEMM writes it).

typedef float  f32x4  __attribute__((ext_vector_type(4)));
typedef __bf16 bf16x8 __attribute__((ext_vector_type(8)));
typedef int    i32x4  __attribute__((ext_vector_type(4)));
typedef unsigned short u16;

__device__ __forceinline__ float b2f(u16 u) {
    unsigned int i = ((unsigned int)u) << 16; float f;
    __builtin_memcpy(&f, &i, 4); return f;
}
__device__ __forceinline__ u16 f2b(float f) {  // round-to-nearest-even
    unsigned int i; __builtin_memcpy(&i, &f, 4);
    i += 0x7FFFu + ((i >> 16) & 1u);
    return (u16)(i >> 16);
}

// ---- mega convert: q,k,v,Wq,Wk,Wv fp32->bf16 + bias gather -----------------
__global__ __launch_bounds__(256) void cvt_all(
    const float4* __restrict__ q, const float4* __restrict__ k,
    const float4* __restrict__ v, const float4* __restrict__ Wq,
    const float4* __restrict__ Wk, const float4* __restrict__ Wv,
    const float* __restrict__ bq, const float* __restrict__ bk,
    const float* __restrict__ bv,
    ushort4* __restrict__ qb, ushort4* __restrict__ kb,
    ushort4* __restrict__ vb, ushort4* __restrict__ Wb,
    float* __restrict__ biasCat)
{
    int bid = blockIdx.x, t = threadIdx.x;
    const float4* s; ushort4* d; int idx;
    if (bid < 8192)       { s = q;  d = qb;            idx = bid * 256 + t; }
    else if (bid < 16384) { s = k;  d = kb;            idx = (bid - 8192) * 256 + t; }
    else if (bid < 24576) { s = v;  d = vb;            idx = (bid - 16384) * 256 + t; }
    else if (bid < 25600) { s = Wq; d = Wb;            idx = (bid - 24576) * 256 + t; }
    else if (bid < 26624) { s = Wk; d = Wb + 262144;   idx = (bid - 25600) * 256 + t; }
    else if (bid < 27648) { s = Wv; d = Wb + 524288;   idx = (bid - 26624) * 256 + t; }
    else {
        for (int i = t; i < 3072; i += 256)
            biasCat[i] = (i < 1024) ? bq[i] : (i < 2048) ? bk[i - 1024] : bv[i - 2048];
        return;
    }
    float4 vv = s[idx];
    ushort4 o;
    o.x = f2b(vv.x); o.y = f2b(vv.y); o.z = f2b(vv.z); o.w = f2b(vv.w);
    d[idx] = o;
}

// ===========================================================================
// 256xBN 8-phase TN GEMM (T2 st_16x32 swizzle + T3/T4 counted vmcnt + T5).
// BK=64, 512 threads = 8 waves (2M x 4N), per-wave 128 x BN/4.
// LDS: A[2buf][2half][128][64] (64 KiB) | B[2buf][2half][BN/2][64].
// BN=256: B halves 8192 elems (2 loads/stage), vmcnt 4, acc[8][4].
// BN=128: B halves 4096 elems (1 load/stage), vmcnt 3, acc[8][2].
// Schedule per K-tile T (cur=T&1): boundary {vmcnt(k); barrier}, then
//  P1: read A-h0,B-g0 | stage B1(T+1)->nxt | bar | lgkm0 | prio MFMA | bar
//  P2: read B-g1      | stage A1(T+1)->nxt | bar | lgkm0 | prio MFMA | bar
//  P3: read A-h1      | stage A0(T+2)->cur | bar | lgkm0 | prio MFMA | bar
//  P4:                | stage B0(T+2)->cur | bar | lgkm0 | prio MFMA | bar
// Race proof as before: boundary vmcnt keeps only the 2 newest stages
// (A0,B0 of T+2) in flight; everything for tile T has landed.
//
// EPI: 0 = dual write fp32 direct + bf16 LDS-coalesced (attn; BN=256);
//      1 = exp(acc+bias)->bf16 LDS-coalesced (proj; BN=128, z==2 -> Calt);
//      2 = fp32 only, direct (out; BN=128).
// ===========================================================================
template<int EPI, int BN>
__global__ __launch_bounds__(512, 2) void gemm256(
    const u16* __restrict__ Ap, const u16* __restrict__ Bp,
    float* __restrict__ C32, u16* __restrict__ C16, u16* __restrict__ Calt,
    const float* __restrict__ bias,
    int N, int K, long long sA, long long sB, long long sC)
{
    constexpr int NB2 = BN / 128;              // B frags per half per wave
    constexpr int BH  = BN * 32;               // B half elems (8192 / 4096)
    constexpr int LDSN = 32768 + 4 * BH;       // u16 elems
    __shared__ __align__(16) u16 lds[LDSN];

    const int tid  = threadIdx.x;
    const int lane = tid & 63;
    const int w    = tid >> 6;
    const int wr   = w >> 2, wc = w & 3;       // 2 x 4 waves

    // XCD swizzle within z-plane (tot divisible by 8)
    const int gx  = gridDim.x;
    const int tot = gx * gridDim.y;
    const int lin = blockIdx.y * gx + blockIdx.x;
    const int vlin = (lin & 7) * (tot >> 3) + (lin >> 3);
    const int bx = vlin % gx, by = vlin / gx;
    const int m0 = by * 256, n0 = bx * BN;
    const int z  = blockIdx.z;

    const u16* Ag = Ap + (size_t)z * sA;
    const u16* Bg = Bp + (size_t)z * sB;

    // staging constants: granule c=tid; logical granule cl = c ^ (bit5(c)<<1)
    // [st_16x32: flip byte-bit5 when byte-bit9 set]
    const int cl = tid ^ ((tid & 32) >> 4);
    const int lr = cl >> 3;                    // local row 0..63
    const int ce = (cl & 7) * 8;               // col element
    const int arow = m0 + lr;                  // + h*64 ; 2nd load +128
    const int brow = (BN == 256) ? (n0 + (lr & 31) + ((lr & 32) << 1))
                                 : (n0 + lr);  // + g*(BN/8)

    // frag-read constants (element offsets within a half)
    const int axr = ((lane >> 2) & 1) << 4;    // read-side swizzle XOR
    const int ar0 = (wr * 64 + (lane & 15)) * 64 + (lane >> 4) * 8;
    const int br0 = (BN == 256)
        ? ((wc * 32 + (lane & 15)) * 64 + (lane >> 4) * 8)
        : ((wc * 16 + (lane & 15)) * 64 + (lane >> 4) * 8);

#define GLL16(gsrc, ldsoff)                                                    \
    __builtin_amdgcn_global_load_lds(                                          \
        (__attribute__((address_space(1))) void*)(uintptr_t)(gsrc),            \
        (__attribute__((address_space(3))) void*)&lds[ldsoff], 16, 0, 0)

#define STAGE_A(c, h, T)                                                       \
    do { const u16* _s = Ag + (size_t)(arow + (h) * 64) * K + (T) * 64 + ce;   \
         int _d = (((c) << 1) + (h)) * 8192 + tid * 8;                         \
         GLL16(_s, _d); GLL16(_s + (size_t)128 * K, _d + 4096); } while (0)

#define STAGE_B(c, g, T)                                                       \
    do { if constexpr (BN == 256) {                                            \
             const u16* _s = Bg + (size_t)(brow + (g) * 32) * K + (T) * 64 + ce; \
             int _d = 32768 + (((c) << 1) + (g)) * 8192 + tid * 8;             \
             GLL16(_s, _d); GLL16(_s + (size_t)128 * K, _d + 4096);            \
         } else {                                                              \
             const u16* _s = Bg + (size_t)(brow + (g) * 64) * K + (T) * 64 + ce; \
             int _d = 32768 + (((c) << 1) + (g)) * 4096 + tid * 8;             \
             GLL16(_s, _d);                                                    \
         } } while (0)

#define SBAR asm volatile("s_barrier" ::: "memory")
#define LGKM0 do { asm volatile("s_waitcnt lgkmcnt(0)" ::: "memory");          \
                   __builtin_amdgcn_sched_barrier(0); } while (0)
#define VMBOUND do { if constexpr (BN == 256)                                  \
                         asm volatile("s_waitcnt vmcnt(4)" ::: "memory");      \
                     else asm volatile("s_waitcnt vmcnt(3)" ::: "memory"); } while (0)

#define LDA(base)                                                              \
    _Pragma("unroll") for (int mi2 = 0; mi2 < 4; ++mi2)                        \
    _Pragma("unroll") for (int ks = 0; ks < 2; ++ks)                           \
        afr[mi2][ks] = __builtin_bit_cast(bf16x8,                              \
            *(const i32x4*)&lds[(base) + ((ar0 + mi2 * 1024 + ks * 32) ^ axr)]);

#define LDB(dst, base)                                                         \
    _Pragma("unroll") for (int ni2 = 0; ni2 < NB2; ++ni2)                      \
    _Pragma("unroll") for (int ks = 0; ks < 2; ++ks)                           \
        dst[ni2][ks] = __builtin_bit_cast(bf16x8,                              \
            *(const i32x4*)&lds[(base) + ((br0 + ni2 * 1024 + ks * 32) ^ axr)]);

#define MFMA_Q(mb, nb, bfrag)                                                  \
    __builtin_amdgcn_s_setprio(1);                                             \
    _Pragma("unroll") for (int mi2 = 0; mi2 < 4; ++mi2)                        \
    _Pragma("unroll") for (int ni2 = 0; ni2 < NB2; ++ni2)                      \
    _Pragma("unroll") for (int ks = 0; ks < 2; ++ks)                           \
        acc[(mb) + mi2][(nb) + ni2] = __builtin_amdgcn_mfma_f32_16x16x32_bf16( \
            afr[mi2][ks], bfrag[ni2][ks], acc[(mb) + mi2][(nb) + ni2], 0, 0, 0); \
    __builtin_amdgcn_s_setprio(0)

    f32x4 acc[8][2 * NB2];
#pragma unroll
    for (int i = 0; i < 8; ++i)
#pragma unroll
        for (int j = 0; j < 2 * NB2; ++j) acc[i][j] = (f32x4)0.0f;

    bf16x8 afr[4][2], b0f[NB2][2], b1f[NB2][2];

    const int nt = K >> 6;

    // prologue: tile0 all 4 halves -> buf0; tile1 A0,B0 -> buf1
    STAGE_A(0, 0, 0); STAGE_B(0, 0, 0);
    STAGE_A(0, 1, 0); STAGE_B(0, 1, 0);
    STAGE_A(1, 0, 1); STAGE_B(1, 0, 1);

    for (int T = 0; T < nt; ++T) {
        const int cur = T & 1, nxt = cur ^ 1;
        const int ab = (cur << 1) * 8192;           // cur A half0 base
        const int bb = 32768 + (cur << 1) * BH;     // cur B half0 base

        if (T + 1 < nt) VMBOUND;
        else            asm volatile("s_waitcnt vmcnt(0)" ::: "memory");
        SBAR;
        // ---- P1: quadrant (h0,g0) ----
        LDA(ab); LDB(b0f, bb);
        if (T + 1 < nt) STAGE_B(nxt, 1, T + 1);
        SBAR; LGKM0;
        MFMA_Q(0, 0, b0f);
        SBAR;
        // ---- P2: (h0,g1) ----
        LDB(b1f, bb + BH);
        if (T + 1 < nt) STAGE_A(nxt, 1, T + 1);
        SBAR; LGKM0;
        MFMA_Q(0, NB2, b1f);
        SBAR;
        // ---- P3: (h1,g0) ----
        LDA(ab + 8192);
        if (T + 2 < nt) STAGE_A(cur, 0, T + 2);
        SBAR; LGKM0;
        MFMA_Q(4, 0, b0f);
        SBAR;
        // ---- P4: (h1,g1) ----
        if (T + 2 < nt) STAGE_B(cur, 0, T + 2);
        SBAR; LGKM0;
        MFMA_Q(4, NB2, b1f);
        SBAR;
    }

    // ------------------------------------------------------------------
    // Epilogue. C row = m0 + wr*128 + mi*16 + (lane>>4)*4 + j.
    // BN=256 col = n0 + wc*64 + ni*16 + (lane&15)   (ni 0..3)
    // BN=128 col = n0 + ni*64 + wc*16 + (lane&15)   (ni 0..1)
    // bf16 outputs staged through LDS, emitted as coalesced dwordx4.
    // ------------------------------------------------------------------
    const int cr0 = m0 + wr * 128 + ((lane >> 4) << 2);

    if constexpr (EPI == 0) {                 // attn: fp32 direct + bf16 via LDS
        const int cc0 = n0 + wc * 64 + (lane & 15);
        float* Cg = C32 + (size_t)z * sC;
#pragma unroll
        for (int mi = 0; mi < 8; ++mi)
#pragma unroll
            for (int ni = 0; ni < 4; ++ni)
#pragma unroll
                for (int j = 0; j < 4; ++j)
                    Cg[(size_t)(cr0 + mi * 16 + j) * N + cc0 + ni * 16] = acc[mi][ni][j];

        u16* sE = lds;                         // [128][264] u16
        u16* Cb = C16 + (size_t)z * sC;
        const int wrow0 = ((lane >> 4) << 2);
        const int wcol0 = wc * 64 + (lane & 15);
        const int rr = tid >> 2;
        const int c0 = (tid & 3) * 8;
        __syncthreads();                       // LDS free (see race proof)
#pragma unroll
        for (int p = 0; p < 2; ++p) {
            if (wr == p) {
#pragma unroll
                for (int mi = 0; mi < 8; ++mi)
#pragma unroll
                    for (int ni = 0; ni < 4; ++ni)
#pragma unroll
                        for (int j = 0; j < 4; ++j)
                            sE[(wrow0 + mi * 16 + j) * 264 + wcol0 + ni * 16] =
                                f2b(acc[mi][ni][j]);
            }
            __syncthreads();
#pragma unroll
            for (int i = 0; i < 8; ++i) {
                i32x4 vv = *(const i32x4*)&sE[rr * 264 + c0 + i * 32];
                *(i32x4*)&Cb[(size_t)(m0 + p * 128 + rr) * N + n0 + c0 + i * 32] = vv;
            }
            if (p == 0) __syncthreads();
        }
    } else if constexpr (EPI == 1) {          // proj (BN=128): exp+bias -> bf16
        u16* sE = lds;                         // [128][136] u16
        u16* Cb = (z == 2) ? Calt : (C16 + (size_t)z * sC);
        const int colb = wc * 16 + (lane & 15);
        const float bv0 = bias[(size_t)z * 1024 + n0 + colb];
        const float bv1 = bias[(size_t)z * 1024 + n0 + 64 + colb];
        const int wrow0 = ((lane >> 4) << 2);
        const int rr = tid >> 2, t4 = tid & 3;
        __syncthreads();
#pragma unroll
        for (int p = 0; p < 2; ++p) {
            if (wr == p) {
#pragma unroll
                for (int mi = 0; mi < 8; ++mi)
#pragma unroll
                    for (int j = 0; j < 4; ++j) {
                        int row = wrow0 + mi * 16 + j;
                        sE[row * 136 + colb]      = f2b(__expf(acc[mi][0][j] + bv0));
                        sE[row * 136 + 64 + colb] = f2b(__expf(acc[mi][1][j] + bv1));
                    }
            }
            __syncthreads();
#pragma unroll
            for (int i = 0; i < 4; ++i) {
                i32x4 vv = *(const i32x4*)&sE[rr * 136 + (t4 + i * 4) * 8];
                *(i32x4*)&Cb[(size_t)(m0 + p * 128 + rr) * N + n0 + (t4 + i * 4) * 8] = vv;
            }
            if (p == 0) __syncthreads();
        }
    } else {                                   // out (BN=128): fp32 direct
        float* Cg = C32 + (size_t)z * sC;
        const int colb = wc * 16 + (lane & 15);
#pragma unroll
        for (int mi = 0; mi < 8; ++mi)
#pragma unroll
            for (int ni = 0; ni < 2; ++ni)
#pragma unroll
                for (int j = 0; j < 4; ++j)
                    Cg[(size_t)(cr0 + mi * 16 + j) * N + n0 + ni * 64 + colb] =
                        acc[mi][ni][j];
    }
#undef GLL16
#undef STAGE_A
#undef STAGE_B
#undef SBAR
#undef LGKM0
#undef VMBOUND
#undef LDA
#undef LDB
#undef MFMA_Q
}

// ---- fused: row softmax (qE) + column partials (kE, vE) --------------------
__global__ __launch_bounds__(256) void sm_partials(
    u16* __restrict__ qE, const u16* __restrict__ kE, const u16* __restrict__ vE,
    float* __restrict__ kpart, float* __restrict__ vpart)
{
    int bid = blockIdx.x, t = threadIdx.x;
    if (bid < 8192) {                          // row softmax over D=1024
        u16* p = qE + (size_t)bid * 1024;
        ushort4 v = *(ushort4*)&p[t * 4];
        float e0 = b2f(v.x), e1 = b2f(v.y), e2 = b2f(v.z), e3 = b2f(v.w);
        float s = (e0 + e1) + (e2 + e3);
#pragma unroll
        for (int off = 32; off; off >>= 1) s += __shfl_down(s, off);
        __shared__ float red[4];
        if ((t & 63) == 0) red[t >> 6] = s;
        __syncthreads();
        float inv = 1.0f / ((red[0] + red[1]) + (red[2] + red[3]));
        ushort4 o;
        o.x = f2b(e0 * inv); o.y = f2b(e1 * inv);
        o.z = f2b(e2 * inv); o.w = f2b(e3 * inv);
        *(ushort4*)&p[t * 4] = o;
    } else {                                   // column partials, 128-row chunks
        int j = bid - 8192;
        const u16* d; float* part;
        if (j < 64) { d = kE; part = kpart; } else { d = vE; part = vpart; j -= 64; }
        int b = j >> 4, c = j & 15;
        const u16* base = d + ((size_t)b * 2048 + c * 128) * 1024 + t * 4;
        float a0 = 0, a1 = 0, a2 = 0, a3 = 0;
        for (int s = 0; s < 128; ++s) {
            ushort4 v = *(const ushort4*)(base + (size_t)s * 1024);
            a0 += b2f(v.x); a1 += b2f(v.y); a2 += b2f(v.z); a3 += b2f(v.w);
        }
        *(float4*)(part + ((size_t)(b * 16 + c)) * 1024 + t * 4) = make_float4(a0, a1, a2, a3);
    }
}

// ---- fused: reduce partials -> kinv, vinv ---------------------------------
__global__ __launch_bounds__(256) void col_reduce2(
    const float* __restrict__ kpart, const float* __restrict__ vpart,
    float* __restrict__ kinv, float* __restrict__ vinv)
{
    int bid = blockIdx.x;
    const float* part; float* inv; float mult;
    if (bid < 16) { part = kpart; inv = kinv; mult = 0.03125f; }
    else          { part = vpart; inv = vinv; mult = 1.0f; bid -= 16; }
    int idx = bid * 256 + threadIdx.x;         // 0..4095 over (b,e)
    int b = idx >> 10, e = idx & 1023;
    float s = 0;
    for (int c = 0; c < 16; ++c) s += part[((size_t)(b * 16 + c)) * 1024 + e];
    inv[idx] = mult / s;
}

// ---- fused: kp in-place col-norm + vp normalize+transpose ------------------
__global__ __launch_bounds__(256) void norm_all(
    u16* __restrict__ kE, const float* __restrict__ kinv,
    const u16* __restrict__ vE, const float* __restrict__ vinv,
    u16* __restrict__ vpT)
{
    int bid = blockIdx.x, t = threadIdx.x;
    if (bid < 8192) {                          // col_norm on kE
        int b = bid >> 11, s = bid & 2047;
        u16* p = kE + ((size_t)b * 2048 + s) * 1024 + t * 4;
        float4 iv = *(const float4*)(kinv + b * 1024 + t * 4);
        ushort4 v = *(ushort4*)p;
        v.x = f2b(b2f(v.x) * iv.x); v.y = f2b(b2f(v.y) * iv.y);
        v.z = f2b(b2f(v.z) * iv.z); v.w = f2b(b2f(v.w) * iv.w);
        *(ushort4*)p = v;
    } else {                                   // transpose+norm vE -> vpT
        __shared__ __align__(16) u16 tile[64][68];
        int j = bid - 8192;
        int b = j >> 9, y = (j >> 5) & 15, x = j & 31;
        int s0 = x * 64, e0 = y * 64;
        int lr = t >> 4, lc = (t & 15) * 4;
#pragma unroll
        for (int i = 0; i < 4; ++i) {
            int sr = i * 16 + lr;
            ushort4 v = *(const ushort4*)(vE + ((size_t)b * 2048 + s0 + sr) * 1024 + e0 + lc);
            tile[sr][lc] = v.x; tile[sr][lc + 1] = v.y;
            tile[sr][lc + 2] = v.z; tile[sr][lc + 3] = v.w;
        }
        __syncthreads();
#pragma unroll
        for (int i = 0; i < 4; ++i) {
            int er = i * 16 + lr;
            float iv = vinv[b * 1024 + e0 + er];
            ushort4 v;
            v.x = f2b(b2f(tile[lc + 0][er]) * iv);
            v.y = f2b(b2f(tile[lc + 1][er]) * iv);
            v.z = f2b(b2f(tile[lc + 2][er]) * iv);
            v.w = f2b(b2f(tile[lc + 3][er]) * iv);
            *(ushort4*)(vpT + ((size_t)b * 1024 + e0 + er) * 2048 + s0 + lc) = v;
        }
    }
}

extern "C" void kernel_launch(void* const* d_in, const int* in_sizes, int n_in,
                              void* d_out, int out_size, void* d_ws, size_t ws_size,
                              hipStream_t stream)
{
    const float* q  = (const float*)d_in[0];
    const float* k  = (const float*)d_in[1];
    const float* v  = (const float*)d_in[2];
    const float* Wq = (const float*)d_in[3];
    const float* bq = (const float*)d_in[4];
    const float* Wk = (const float*)d_in[5];
    const float* bk = (const float*)d_in[6];
    const float* Wv = (const float*)d_in[7];
    const float* bv = (const float*)d_in[8];

    float* out  = (float*)d_out;          // [4,2048,1024] fp32
    float* attn = out + 8388608;          // [4,2048,2048] fp32

    u16* wsU = (u16*)d_ws;
    u16* qE   = wsU;                      // R0: exp'd q logits -> qp
    u16* kE   = wsU + 8388608;            // R1: exp'd k logits -> kp
    u16* Wb   = wsU + 16777216;           // R2: Wqb|Wkb|Wvb (stride 1M)
    u16* qb   = wsU + 25165824;           // R3: q bf16 (dead after proj)
    u16* kb   = wsU + 33554432;           // R4: k bf16 (dead after proj)
    u16* vb   = wsU + 41943040;           // R4+8.4M: v bf16 (dead after proj)
    u16* vpT  = wsU + 25165824;           // R3 after proj: vpT [4,1024,2048]
    u16* attnB = wsU + 33554432;          // R4 after proj: attn bf16
    u16* vE   = (u16*)attn;               // d_out attn region as scratch

    float* tail  = (float*)(wsU + 50331648);
    float* kpart = tail;                  // [4,16,1024]
    float* vpart = tail + 65536;
    float* kinv  = tail + 131072;         // [4,1024]
    float* vinv  = tail + 135168;
    float* biasCat = tail + 139264;       // [3,1024] bq|bk|bv

    const long long SD = 2048LL * 1024, SS = 2048LL * 2048, DS = 1024LL * 2048;

    // ---- 1: convert inputs + weights to bf16, gather biases ----
    cvt_all<<<dim3(27649), dim3(256), 0, stream>>>(
        (const float4*)q, (const float4*)k, (const float4*)v,
        (const float4*)Wq, (const float4*)Wk, (const float4*)Wv,
        bq, bk, bv,
        (ushort4*)qb, (ushort4*)kb, (ushort4*)vb, (ushort4*)Wb, biasCat);

    // ---- 2: batched projections (256x128 tile): z=0/1/2 -> qE, kE, vE ----
    gemm256<1, 128><<<dim3(8, 32, 3), dim3(512), 0, stream>>>(
        qb, Wb, nullptr, qE, vE, biasCat,
        1024, 1024, 8388608LL, 1048576LL, 8388608LL);

    // ---- 3: row softmax (qE) + col partials (kE, vE) ----
    sm_partials<<<dim3(8320), dim3(256), 0, stream>>>(qE, kE, vE, kpart, vpart);

    // ---- 4: reduce -> kinv (x 1/32), vinv ----
    col_reduce2<<<dim3(32), dim3(256), 0, stream>>>(kpart, vpart, kinv, vinv);

    // ---- 5: kp col-norm in place + vp normalize+transpose -> vpT ----
    norm_all<<<dim3(10240), dim3(256), 0, stream>>>(kE, kinv, vE, vinv, vpT);

    // ---- 6: attn = qp @ kp^T -> fp32 d_out + bf16 ws copy (256x256) ----
    gemm256<0, 256><<<dim3(8, 8, 4), dim3(512), 0, stream>>>(
        qE, kE, attn, attnB, nullptr, nullptr, 2048, 1024, SD, SD, SS);

    // ---- 7: out = attnB @ vpT^T -> fp32 d_out (256x128, 256 blocks) ----
    gemm256<2, 128><<<dim3(8, 8, 4), dim3(512), 0, stream>>>(
        attnB, vpT, out, nullptr, nullptr, nullptr, 1024, 2048, SS, DS, SD);
}

// Round 4
// 224.027 us; speedup vs baseline: 1.2951x; 1.0953x over previous
//
#include <hip/hip_runtime.h>
#include <math.h>

// LinearAttention B=4, S=2048, D=1024 — bf16 MFMA; ALL big GEMMs on the 8-phase
// template family.
// R4: BN=128 path rebuilt as a merged 2-phase / 1-barrier-per-phase schedule
// (16 MFMA per barrier, counted vmcnt(6)); epilogue LDS staging made
// bank-conflict-free via col XOR ((row>>2)&3)<<4. BN=256 (attn) keeps the
// proven 4-phase schedule.
//   proj: 256x128, grid 8x32x3 = 768 blocks (3 rounds)
//   attn: 256x256, grid 8x8x4  = 256 blocks (1 round)
//   out : 256x128, grid 8x8x4  = 256 blocks (1 round)
//
// Workspace map (u16 elems):
//   R0 [0,        8388608): qE  (exp'd q logits -> qp bf16)
//   R1 [8388608, 16777216): kE
//   R2 [16777216,25165824): Wqb@+0, Wkb@+1M, Wvb@+2M (dead after proj)
//   R3 [25165824,33554432): qb (dead after proj) -> vpT [4,1024,2048]
//   R4 [33554432,50331648): kb@+0, vb@+8.4M (dead after proj) -> attnB bf16
//   tail @ 50331648 (floats): kpart, vpart, kinv, vinv, biasCat[3][1024]
//   vE lives in d_out's attn region as u16 scratch (dead before attn GEMM writes it).

typedef float  f32x4  __attribute__((ext_vector_type(4)));
typedef __bf16 bf16x8 __attribute__((ext_vector_type(8)));
typedef int    i32x4  __attribute__((ext_vector_type(4)));
typedef unsigned short u16;

__device__ __forceinline__ float b2f(u16 u) {
    unsigned int i = ((unsigned int)u) << 16; float f;
    __builtin_memcpy(&f, &i, 4); return f;
}
__device__ __forceinline__ u16 f2b(float f) {  // round-to-nearest-even
    unsigned int i; __builtin_memcpy(&i, &f, 4);
    i += 0x7FFFu + ((i >> 16) & 1u);
    return (u16)(i >> 16);
}

// ---- mega convert: q,k,v,Wq,Wk,Wv fp32->bf16 + bias gather -----------------
__global__ __launch_bounds__(256) void cvt_all(
    const float4* __restrict__ q, const float4* __restrict__ k,
    const float4* __restrict__ v, const float4* __restrict__ Wq,
    const float4* __restrict__ Wk, const float4* __restrict__ Wv,
    const float* __restrict__ bq, const float* __restrict__ bk,
    const float* __restrict__ bv,
    ushort4* __restrict__ qb, ushort4* __restrict__ kb,
    ushort4* __restrict__ vb, ushort4* __restrict__ Wb,
    float* __restrict__ biasCat)
{
    int bid = blockIdx.x, t = threadIdx.x;
    const float4* s; ushort4* d; int idx;
    if (bid < 8192)       { s = q;  d = qb;            idx = bid * 256 + t; }
    else if (bid < 16384) { s = k;  d = kb;            idx = (bid - 8192) * 256 + t; }
    else if (bid < 24576) { s = v;  d = vb;            idx = (bid - 16384) * 256 + t; }
    else if (bid < 25600) { s = Wq; d = Wb;            idx = (bid - 24576) * 256 + t; }
    else if (bid < 26624) { s = Wk; d = Wb + 262144;   idx = (bid - 25600) * 256 + t; }
    else if (bid < 27648) { s = Wv; d = Wb + 524288;   idx = (bid - 26624) * 256 + t; }
    else {
        for (int i = t; i < 3072; i += 256)
            biasCat[i] = (i < 1024) ? bq[i] : (i < 2048) ? bk[i - 1024] : bv[i - 2048];
        return;
    }
    float4 vv = s[idx];
    ushort4 o;
    o.x = f2b(vv.x); o.y = f2b(vv.y); o.z = f2b(vv.z); o.w = f2b(vv.w);
    d[idx] = o;
}

// ===========================================================================
// 256xBN TN GEMM (T2 st_16x32 swizzle + counted vmcnt + T5 setprio).
// BK=64, 512 threads = 8 waves (2M x 4N), per-wave 128 x BN/4.
// LDS: A[2buf][2half][128][64] (64 KiB) | B[2buf][2half][BN/2][64].
//
// BN=256 (attn): proven 4-phase schedule, boundary vmcnt(4), 9 barriers/tile.
// BN=128 (proj/out): merged 2-phase, ONE barrier per phase:
//   P1: {vmcnt(6); bar} read A-h0,B-g0,B-g1 | stage A-h1(T+1)->nxt | lgkm0 |
//       prio 16xMFMA (acc rows 0-3, both col halves)
//   P2: {vmcnt(6); bar} read A-h1            | stage G1(T+2)->cur  | lgkm0 |
//       prio 16xMFMA (acc rows 4-7)
//   G1 = {A-h0(2 GLL), B-g0(1), B-g1(1)}; A-h1 = 2 GLL.
//   vmcnt proof (per-wave issue order ... A-h1(T)@P1(T-1), G1(T+1)@P2(T-1),
//   A-h1(T+1)@P1(T), G1(T+2)@P2(T) ...):
//     P1(T) needs G1(T): newest-6 = {G1(T+1)4, A-h1(T)2} -> vmcnt(6).
//     P2(T) needs A-h1(T): newest-6 = {A-h1(T+1)2, G1(T+1)4} -> vmcnt(6).
//     Tail: P1(nt-1) -> vmcnt(2), P2(nt-1) -> vmcnt(0).
//   Region safety: each staged region's last reader retired at its lgkm0 in
//   an earlier phase; the staging wave issues only after the phase-start
//   barrier that follows that lgkm0.
//   Per-element accumulation order identical to the 4-phase schedule.
//
// EPI: 0 = dual write fp32 direct + bf16 LDS-coalesced (attn; BN=256);
//      1 = exp(acc+bias)->bf16 LDS-coalesced (proj; BN=128, z==2 -> Calt);
//      2 = fp32 only, direct (out; BN=128).
// Epilogue LDS staging col-XOR'd by ((row>>2)&3)<<4 -> the 4 row-groups of a
// store instruction land on distinct bank quads (conflict-free for EPI=1).
// ===========================================================================
template<int EPI, int BN>
__global__ __launch_bounds__(512, 2) void gemm256(
    const u16* __restrict__ Ap, const u16* __restrict__ Bp,
    float* __restrict__ C32, u16* __restrict__ C16, u16* __restrict__ Calt,
    const float* __restrict__ bias,
    int N, int K, long long sA, long long sB, long long sC)
{
    constexpr int NB2 = BN / 128;              // B frags per half per wave
    constexpr int BH  = BN * 32;               // B half elems (8192 / 4096)
    constexpr int LDSN = 32768 + 4 * BH;       // u16 elems
    __shared__ __align__(16) u16 lds[LDSN];

    const int tid  = threadIdx.x;
    const int lane = tid & 63;
    const int w    = tid >> 6;
    const int wr   = w >> 2, wc = w & 3;       // 2 x 4 waves

    // XCD swizzle within z-plane (tot divisible by 8)
    const int gx  = gridDim.x;
    const int tot = gx * gridDim.y;
    const int lin = blockIdx.y * gx + blockIdx.x;
    const int vlin = (lin & 7) * (tot >> 3) + (lin >> 3);
    const int bx = vlin % gx, by = vlin / gx;
    const int m0 = by * 256, n0 = bx * BN;
    const int z  = blockIdx.z;

    const u16* Ag = Ap + (size_t)z * sA;
    const u16* Bg = Bp + (size_t)z * sB;

    // staging constants: granule c=tid; logical granule cl = c ^ (bit5(c)<<1)
    // [st_16x32: flip byte-bit5 when byte-bit9 set]
    const int cl = tid ^ ((tid & 32) >> 4);
    const int lr = cl >> 3;                    // local row 0..63
    const int ce = (cl & 7) * 8;               // col element
    const int arow = m0 + lr;                  // + h*64 ; 2nd load +128
    const int brow = (BN == 256) ? (n0 + (lr & 31) + ((lr & 32) << 1))
                                 : (n0 + lr);  // + g*(BN/8)

    // frag-read constants (element offsets within a half)
    const int axr = ((lane >> 2) & 1) << 4;    // read-side swizzle XOR
    const int ar0 = (wr * 64 + (lane & 15)) * 64 + (lane >> 4) * 8;
    const int br0 = (BN == 256)
        ? ((wc * 32 + (lane & 15)) * 64 + (lane >> 4) * 8)
        : ((wc * 16 + (lane & 15)) * 64 + (lane >> 4) * 8);

#define GLL16(gsrc, ldsoff)                                                    \
    __builtin_amdgcn_global_load_lds(                                          \
        (__attribute__((address_space(1))) void*)(uintptr_t)(gsrc),            \
        (__attribute__((address_space(3))) void*)&lds[ldsoff], 16, 0, 0)

#define STAGE_A(c, h, T)                                                       \
    do { const u16* _s = Ag + (size_t)(arow + (h) * 64) * K + (T) * 64 + ce;   \
         int _d = (((c) << 1) + (h)) * 8192 + tid * 8;                         \
         GLL16(_s, _d); GLL16(_s + (size_t)128 * K, _d + 4096); } while (0)

#define STAGE_B(c, g, T)                                                       \
    do { if constexpr (BN == 256) {                                            \
             const u16* _s = Bg + (size_t)(brow + (g) * 32) * K + (T) * 64 + ce; \
             int _d = 32768 + (((c) << 1) + (g)) * 8192 + tid * 8;             \
             GLL16(_s, _d); GLL16(_s + (size_t)128 * K, _d + 4096);            \
         } else {                                                              \
             const u16* _s = Bg + (size_t)(brow + (g) * 64) * K + (T) * 64 + ce; \
             int _d = 32768 + (((c) << 1) + (g)) * 4096 + tid * 8;             \
             GLL16(_s, _d);                                                    \
         } } while (0)

#define SBAR asm volatile("s_barrier" ::: "memory")
#define LGKM0 do { asm volatile("s_waitcnt lgkmcnt(0)" ::: "memory");          \
                   __builtin_amdgcn_sched_barrier(0); } while (0)

#define LDA(base)                                                              \
    _Pragma("unroll") for (int mi2 = 0; mi2 < 4; ++mi2)                        \
    _Pragma("unroll") for (int ks = 0; ks < 2; ++ks)                           \
        afr[mi2][ks] = __builtin_bit_cast(bf16x8,                              \
            *(const i32x4*)&lds[(base) + ((ar0 + mi2 * 1024 + ks * 32) ^ axr)]);

#define LDB(dst, base)                                                         \
    _Pragma("unroll") for (int ni2 = 0; ni2 < NB2; ++ni2)                      \
    _Pragma("unroll") for (int ks = 0; ks < 2; ++ks)                           \
        dst[ni2][ks] = __builtin_bit_cast(bf16x8,                              \
            *(const i32x4*)&lds[(base) + ((br0 + ni2 * 1024 + ks * 32) ^ axr)]);

#define MFMA_Q(mb, nb, bfrag)                                                  \
    __builtin_amdgcn_s_setprio(1);                                             \
    _Pragma("unroll") for (int mi2 = 0; mi2 < 4; ++mi2)                        \
    _Pragma("unroll") for (int ni2 = 0; ni2 < NB2; ++ni2)                      \
    _Pragma("unroll") for (int ks = 0; ks < 2; ++ks)                           \
        acc[(mb) + mi2][(nb) + ni2] = __builtin_amdgcn_mfma_f32_16x16x32_bf16( \
            afr[mi2][ks], bfrag[ni2][ks], acc[(mb) + mi2][(nb) + ni2], 0, 0, 0); \
    __builtin_amdgcn_s_setprio(0)

    f32x4 acc[8][2 * NB2];
#pragma unroll
    for (int i = 0; i < 8; ++i)
#pragma unroll
        for (int j = 0; j < 2 * NB2; ++j) acc[i][j] = (f32x4)0.0f;

    bf16x8 afr[4][2], b0f[NB2][2], b1f[NB2][2];

    const int nt = K >> 6;

    if constexpr (BN == 256) {
        // -------- proven 4-phase schedule (attn) --------
        STAGE_A(0, 0, 0); STAGE_B(0, 0, 0);
        STAGE_A(0, 1, 0); STAGE_B(0, 1, 0);
        STAGE_A(1, 0, 1); STAGE_B(1, 0, 1);

        for (int T = 0; T < nt; ++T) {
            const int cur = T & 1, nxt = cur ^ 1;
            const int ab = (cur << 1) * 8192;
            const int bb = 32768 + (cur << 1) * BH;

            if (T + 1 < nt) asm volatile("s_waitcnt vmcnt(4)" ::: "memory");
            else            asm volatile("s_waitcnt vmcnt(0)" ::: "memory");
            SBAR;
            LDA(ab); LDB(b0f, bb);
            if (T + 1 < nt) STAGE_B(nxt, 1, T + 1);
            SBAR; LGKM0;
            MFMA_Q(0, 0, b0f);
            SBAR;
            LDB(b1f, bb + BH);
            if (T + 1 < nt) STAGE_A(nxt, 1, T + 1);
            SBAR; LGKM0;
            MFMA_Q(0, NB2, b1f);
            SBAR;
            LDA(ab + 8192);
            if (T + 2 < nt) STAGE_A(cur, 0, T + 2);
            SBAR; LGKM0;
            MFMA_Q(4, 0, b0f);
            SBAR;
            if (T + 2 < nt) STAGE_B(cur, 0, T + 2);
            SBAR; LGKM0;
            MFMA_Q(4, NB2, b1f);
            SBAR;
        }
    } else {
        // -------- merged 2-phase schedule (proj/out) --------
        // prologue issue order (per wave): G1(0), A-h1(0), G1(1)
        STAGE_A(0, 0, 0); STAGE_B(0, 0, 0); STAGE_B(0, 1, 0);   // G1(0)->buf0
        STAGE_A(0, 1, 0);                                        // A-h1(0)->buf0
        STAGE_A(1, 0, 1); STAGE_B(1, 0, 1); STAGE_B(1, 1, 1);   // G1(1)->buf1

        for (int T = 0; T < nt; ++T) {
            const int cur = T & 1, nxt = cur ^ 1;
            const int ab = (cur << 1) * 8192;
            const int bb = 32768 + (cur << 1) * BH;

            // ---- P1 ----
            if (T + 1 < nt) asm volatile("s_waitcnt vmcnt(6)" ::: "memory");
            else            asm volatile("s_waitcnt vmcnt(2)" ::: "memory");
            SBAR;
            LDA(ab); LDB(b0f, bb); LDB(b1f, bb + BH);
            if (T + 1 < nt) STAGE_A(nxt, 1, T + 1);
            LGKM0;
            MFMA_Q(0, 0, b0f); MFMA_Q(0, 1, b1f);

            // ---- P2 ----
            if (T + 1 < nt) asm volatile("s_waitcnt vmcnt(6)" ::: "memory");
            else            asm volatile("s_waitcnt vmcnt(0)" ::: "memory");
            SBAR;
            LDA(ab + 8192);
            if (T + 2 < nt) { STAGE_A(cur, 0, T + 2); STAGE_B(cur, 0, T + 2);
                              STAGE_B(cur, 1, T + 2); }
            LGKM0;
            MFMA_Q(4, 0, b0f); MFMA_Q(4, 1, b1f);
        }
    }

    // ------------------------------------------------------------------
    // Epilogue. C row = m0 + wr*128 + mi*16 + (lane>>4)*4 + j.
    // BN=256 col = n0 + wc*64 + ni*16 + (lane&15)   (ni 0..3)
    // BN=128 col = n0 + ni*64 + wc*16 + (lane&15)   (ni 0..1)
    // bf16 outputs staged through LDS with col XOR ((row>>2)&3)<<4
    // (bank-quad separation of the 4 row-groups), emitted as dwordx4.
    // ------------------------------------------------------------------
    const int cr0 = m0 + wr * 128 + ((lane >> 4) << 2);

    if constexpr (EPI == 0) {                 // attn: fp32 direct + bf16 via LDS
        const int cc0 = n0 + wc * 64 + (lane & 15);
        float* Cg = C32 + (size_t)z * sC;
#pragma unroll
        for (int mi = 0; mi < 8; ++mi)
#pragma unroll
            for (int ni = 0; ni < 4; ++ni)
#pragma unroll
                for (int j = 0; j < 4; ++j)
                    Cg[(size_t)(cr0 + mi * 16 + j) * N + cc0 + ni * 16] = acc[mi][ni][j];

        u16* sE = lds;                         // [128][264] u16
        u16* Cb = C16 + (size_t)z * sC;
        const int wrow0 = ((lane >> 4) << 2);
        const int wcol0 = wc * 64 + (lane & 15);
        const int rr = tid >> 2;
        const int c0 = (tid & 3) * 8;
        const int rxor = ((rr >> 2) & 3) << 4;
        __syncthreads();                       // LDS free (loop fully drained)
#pragma unroll
        for (int p = 0; p < 2; ++p) {
            if (wr == p) {
#pragma unroll
                for (int mi = 0; mi < 8; ++mi)
#pragma unroll
                    for (int j = 0; j < 4; ++j) {
                        int row = wrow0 + mi * 16 + j;
                        int cx = ((row >> 2) & 3) << 4;
#pragma unroll
                        for (int ni = 0; ni < 4; ++ni)
                            sE[row * 264 + ((wcol0 + ni * 16) ^ cx)] =
                                f2b(acc[mi][ni][j]);
                    }
            }
            __syncthreads();
#pragma unroll
            for (int i = 0; i < 8; ++i) {
                i32x4 vv = *(const i32x4*)&sE[rr * 264 + ((c0 + i * 32) ^ rxor)];
                *(i32x4*)&Cb[(size_t)(m0 + p * 128 + rr) * N + n0 + c0 + i * 32] = vv;
            }
            if (p == 0) __syncthreads();
        }
    } else if constexpr (EPI == 1) {          // proj (BN=128): exp+bias -> bf16
        u16* sE = lds;                         // [128][136] u16
        u16* Cb = (z == 2) ? Calt : (C16 + (size_t)z * sC);
        const int colb = wc * 16 + (lane & 15);
        const float bv0 = bias[(size_t)z * 1024 + n0 + colb];
        const float bv1 = bias[(size_t)z * 1024 + n0 + 64 + colb];
        const int wrow0 = ((lane >> 4) << 2);
        const int rr = tid >> 2, t4 = tid & 3;
        const int rxor = ((rr >> 2) & 3) << 4;
        __syncthreads();
#pragma unroll
        for (int p = 0; p < 2; ++p) {
            if (wr == p) {
#pragma unroll
                for (int mi = 0; mi < 8; ++mi)
#pragma unroll
                    for (int j = 0; j < 4; ++j) {
                        int row = wrow0 + mi * 16 + j;
                        int cx = ((row >> 2) & 3) << 4;
                        sE[row * 136 + (colb ^ cx)]        = f2b(__expf(acc[mi][0][j] + bv0));
                        sE[row * 136 + ((64 + colb) ^ cx)] = f2b(__expf(acc[mi][1][j] + bv1));
                    }
            }
            __syncthreads();
#pragma unroll
            for (int i = 0; i < 4; ++i) {
                i32x4 vv = *(const i32x4*)&sE[rr * 136 + (((t4 + i * 4) * 8) ^ rxor)];
                *(i32x4*)&Cb[(size_t)(m0 + p * 128 + rr) * N + n0 + (t4 + i * 4) * 8] = vv;
            }
            if (p == 0) __syncthreads();
        }
    } else {                                   // out (BN=128): fp32 direct
        float* Cg = C32 + (size_t)z * sC;
        const int colb = wc * 16 + (lane & 15);
#pragma unroll
        for (int mi = 0; mi < 8; ++mi)
#pragma unroll
            for (int ni = 0; ni < 2; ++ni)
#pragma unroll
                for (int j = 0; j < 4; ++j)
                    Cg[(size_t)(cr0 + mi * 16 + j) * N + n0 + ni * 64 + colb] =
                        acc[mi][ni][j];
    }
#undef GLL16
#undef STAGE_A
#undef STAGE_B
#undef SBAR
#undef LGKM0
#undef LDA
#undef LDB
#undef MFMA_Q
}

// ---- fused: row softmax (qE) + column partials (kE, vE) --------------------
__global__ __launch_bounds__(256) void sm_partials(
    u16* __restrict__ qE, const u16* __restrict__ kE, const u16* __restrict__ vE,
    float* __restrict__ kpart, float* __restrict__ vpart)
{
    int bid = blockIdx.x, t = threadIdx.x;
    if (bid < 8192) {                          // row softmax over D=1024
        u16* p = qE + (size_t)bid * 1024;
        ushort4 v = *(ushort4*)&p[t * 4];
        float e0 = b2f(v.x), e1 = b2f(v.y), e2 = b2f(v.z), e3 = b2f(v.w);
        float s = (e0 + e1) + (e2 + e3);
#pragma unroll
        for (int off = 32; off; off >>= 1) s += __shfl_down(s, off);
        __shared__ float red[4];
        if ((t & 63) == 0) red[t >> 6] = s;
        __syncthreads();
        float inv = 1.0f / ((red[0] + red[1]) + (red[2] + red[3]));
        ushort4 o;
        o.x = f2b(e0 * inv); o.y = f2b(e1 * inv);
        o.z = f2b(e2 * inv); o.w = f2b(e3 * inv);
        *(ushort4*)&p[t * 4] = o;
    } else {                                   // column partials, 128-row chunks
        int j = bid - 8192;
        const u16* d; float* part;
        if (j < 64) { d = kE; part = kpart; } else { d = vE; part = vpart; j -= 64; }
        int b = j >> 4, c = j & 15;
        const u16* base = d + ((size_t)b * 2048 + c * 128) * 1024 + t * 4;
        float a0 = 0, a1 = 0, a2 = 0, a3 = 0;
        for (int s = 0; s < 128; ++s) {
            ushort4 v = *(const ushort4*)(base + (size_t)s * 1024);
            a0 += b2f(v.x); a1 += b2f(v.y); a2 += b2f(v.z); a3 += b2f(v.w);
        }
        *(float4*)(part + ((size_t)(b * 16 + c)) * 1024 + t * 4) = make_float4(a0, a1, a2, a3);
    }
}

// ---- fused: reduce partials -> kinv, vinv ---------------------------------
__global__ __launch_bounds__(256) void col_reduce2(
    const float* __restrict__ kpart, const float* __restrict__ vpart,
    float* __restrict__ kinv, float* __restrict__ vinv)
{
    int bid = blockIdx.x;
    const float* part; float* inv; float mult;
    if (bid < 16) { part = kpart; inv = kinv; mult = 0.03125f; }
    else          { part = vpart; inv = vinv; mult = 1.0f; bid -= 16; }
    int idx = bid * 256 + threadIdx.x;         // 0..4095 over (b,e)
    int b = idx >> 10, e = idx & 1023;
    float s = 0;
    for (int c = 0; c < 16; ++c) s += part[((size_t)(b * 16 + c)) * 1024 + e];
    inv[idx] = mult / s;
}

// ---- fused: kp in-place col-norm + vp normalize+transpose ------------------
__global__ __launch_bounds__(256) void norm_all(
    u16* __restrict__ kE, const float* __restrict__ kinv,
    const u16* __restrict__ vE, const float* __restrict__ vinv,
    u16* __restrict__ vpT)
{
    int bid = blockIdx.x, t = threadIdx.x;
    if (bid < 8192) {                          // col_norm on kE
        int b = bid >> 11, s = bid & 2047;
        u16* p = kE + ((size_t)b * 2048 + s) * 1024 + t * 4;
        float4 iv = *(const float4*)(kinv + b * 1024 + t * 4);
        ushort4 v = *(ushort4*)p;
        v.x = f2b(b2f(v.x) * iv.x); v.y = f2b(b2f(v.y) * iv.y);
        v.z = f2b(b2f(v.z) * iv.z); v.w = f2b(b2f(v.w) * iv.w);
        *(ushort4*)p = v;
    } else {                                   // transpose+norm vE -> vpT
        __shared__ __align__(16) u16 tile[64][68];
        int j = bid - 8192;
        int b = j >> 9, y = (j >> 5) & 15, x = j & 31;
        int s0 = x * 64, e0 = y * 64;
        int lr = t >> 4, lc = (t & 15) * 4;
#pragma unroll
        for (int i = 0; i < 4; ++i) {
            int sr = i * 16 + lr;
            ushort4 v = *(const ushort4*)(vE + ((size_t)b * 2048 + s0 + sr) * 1024 + e0 + lc);
            tile[sr][lc] = v.x; tile[sr][lc + 1] = v.y;
            tile[sr][lc + 2] = v.z; tile[sr][lc + 3] = v.w;
        }
        __syncthreads();
#pragma unroll
        for (int i = 0; i < 4; ++i) {
            int er = i * 16 + lr;
            float iv = vinv[b * 1024 + e0 + er];
            ushort4 v;
            v.x = f2b(b2f(tile[lc + 0][er]) * iv);
            v.y = f2b(b2f(tile[lc + 1][er]) * iv);
            v.z = f2b(b2f(tile[lc + 2][er]) * iv);
            v.w = f2b(b2f(tile[lc + 3][er]) * iv);
            *(ushort4*)(vpT + ((size_t)b * 1024 + e0 + er) * 2048 + s0 + lc) = v;
        }
    }
}

extern "C" void kernel_launch(void* const* d_in, const int* in_sizes, int n_in,
                              void* d_out, int out_size, void* d_ws, size_t ws_size,
                              hipStream_t stream)
{
    const float* q  = (const float*)d_in[0];
    const float* k  = (const float*)d_in[1];
    const float* v  = (const float*)d_in[2];
    const float* Wq = (const float*)d_in[3];
    const float* bq = (const float*)d_in[4];
    const float* Wk = (const float*)d_in[5];
    const float* bk = (const float*)d_in[6];
    const float* Wv = (const float*)d_in[7];
    const float* bv = (const float*)d_in[8];

    float* out  = (float*)d_out;          // [4,2048,1024] fp32
    float* attn = out + 8388608;          // [4,2048,2048] fp32

    u16* wsU = (u16*)d_ws;
    u16* qE   = wsU;                      // R0: exp'd q logits -> qp
    u16* kE   = wsU + 8388608;            // R1: exp'd k logits -> kp
    u16* Wb   = wsU + 16777216;           // R2: Wqb|Wkb|Wvb (stride 1M)
    u16* qb   = wsU + 25165824;           // R3: q bf16 (dead after proj)
    u16* kb   = wsU + 33554432;           // R4: k bf16 (dead after proj)
    u16* vb   = wsU + 41943040;           // R4+8.4M: v bf16 (dead after proj)
    u16* vpT  = wsU + 25165824;           // R3 after proj: vpT [4,1024,2048]
    u16* attnB = wsU + 33554432;          // R4 after proj: attn bf16
    u16* vE   = (u16*)attn;               // d_out attn region as scratch

    float* tail  = (float*)(wsU + 50331648);
    float* kpart = tail;                  // [4,16,1024]
    float* vpart = tail + 65536;
    float* kinv  = tail + 131072;         // [4,1024]
    float* vinv  = tail + 135168;
    float* biasCat = tail + 139264;       // [3,1024] bq|bk|bv

    const long long SD = 2048LL * 1024, SS = 2048LL * 2048, DS = 1024LL * 2048;

    // ---- 1: convert inputs + weights to bf16, gather biases ----
    cvt_all<<<dim3(27649), dim3(256), 0, stream>>>(
        (const float4*)q, (const float4*)k, (const float4*)v,
        (const float4*)Wq, (const float4*)Wk, (const float4*)Wv,
        bq, bk, bv,
        (ushort4*)qb, (ushort4*)kb, (ushort4*)vb, (ushort4*)Wb, biasCat);

    // ---- 2: batched projections (256x128, 2-phase): z=0/1/2 -> qE, kE, vE ----
    gemm256<1, 128><<<dim3(8, 32, 3), dim3(512), 0, stream>>>(
        qb, Wb, nullptr, qE, vE, biasCat,
        1024, 1024, 8388608LL, 1048576LL, 8388608LL);

    // ---- 3: row softmax (qE) + col partials (kE, vE) ----
    sm_partials<<<dim3(8320), dim3(256), 0, stream>>>(qE, kE, vE, kpart, vpart);

    // ---- 4: reduce -> kinv (x 1/32), vinv ----
    col_reduce2<<<dim3(32), dim3(256), 0, stream>>>(kpart, vpart, kinv, vinv);

    // ---- 5: kp col-norm in place + vp normalize+transpose -> vpT ----
    norm_all<<<dim3(10240), dim3(256), 0, stream>>>(kE, kinv, vE, vinv, vpT);

    // ---- 6: attn = qp @ kp^T -> fp32 d_out + bf16 ws copy (256x256) ----
    gemm256<0, 256><<<dim3(8, 8, 4), dim3(512), 0, stream>>>(
        qE, kE, attn, attnB, nullptr, nullptr, 2048, 1024, SD, SD, SS);

    // ---- 7: out = attnB @ vpT^T -> fp32 d_out (256x128, 2-phase) ----
    gemm256<2, 128><<<dim3(8, 8, 4), dim3(512), 0, stream>>>(
        attnB, vpT, out, nullptr, nullptr, nullptr, 1024, 2048, SS, DS, SD);
}

// Round 5
// 222.073 us; speedup vs baseline: 1.3065x; 1.0088x over previous
//
#include <hip/hip_runtime.h>
#include <math.h>

// LinearAttention B=4, S=2048, D=1024 — bf16 MFMA; ALL big GEMMs on the 8-phase
// template family.
// R5: fixed the LDS swizzle to the full 2-bit st_16x32 involution
// (byte ^= ((byte>>9)&3)<<5). The old 1-bit variant left every ds_read_b128
// on 16 of 32 banks (2x read time, 8.26M conflict cycles measured). Stage
// side: granule cl = tid ^ ((tid>>4)&6); read side: axr = ((lane>>2)&3)<<4.
//   proj: 256x128 2-phase, grid 8x32x3 = 768 blocks (3 rounds)
//   attn: 256x256 4-phase, grid 8x8x4  = 256 blocks (1 round)
//   out : 256x128 2-phase, grid 8x8x4  = 256 blocks (1 round)
//
// Workspace map (u16 elems):
//   R0 [0,        8388608): qE  (exp'd q logits -> qp bf16)
//   R1 [8388608, 16777216): kE
//   R2 [16777216,25165824): Wqb@+0, Wkb@+1M, Wvb@+2M (dead after proj)
//   R3 [25165824,33554432): qb (dead after proj) -> vpT [4,1024,2048]
//   R4 [33554432,50331648): kb@+0, vb@+8.4M (dead after proj) -> attnB bf16
//   tail @ 50331648 (floats): kpart, vpart, kinv, vinv, biasCat[3][1024]
//   vE lives in d_out's attn region as u16 scratch (dead before attn GEMM writes it).

typedef float  f32x4  __attribute__((ext_vector_type(4)));
typedef __bf16 bf16x8 __attribute__((ext_vector_type(8)));
typedef int    i32x4  __attribute__((ext_vector_type(4)));
typedef unsigned short u16;

__device__ __forceinline__ float b2f(u16 u) {
    unsigned int i = ((unsigned int)u) << 16; float f;
    __builtin_memcpy(&f, &i, 4); return f;
}
__device__ __forceinline__ u16 f2b(float f) {  // round-to-nearest-even
    unsigned int i; __builtin_memcpy(&i, &f, 4);
    i += 0x7FFFu + ((i >> 16) & 1u);
    return (u16)(i >> 16);
}

// ---- mega convert: q,k,v,Wq,Wk,Wv fp32->bf16 + bias gather -----------------
__global__ __launch_bounds__(256) void cvt_all(
    const float4* __restrict__ q, const float4* __restrict__ k,
    const float4* __restrict__ v, const float4* __restrict__ Wq,
    const float4* __restrict__ Wk, const float4* __restrict__ Wv,
    const float* __restrict__ bq, const float* __restrict__ bk,
    const float* __restrict__ bv,
    ushort4* __restrict__ qb, ushort4* __restrict__ kb,
    ushort4* __restrict__ vb, ushort4* __restrict__ Wb,
    float* __restrict__ biasCat)
{
    int bid = blockIdx.x, t = threadIdx.x;
    const float4* s; ushort4* d; int idx;
    if (bid < 8192)       { s = q;  d = qb;            idx = bid * 256 + t; }
    else if (bid < 16384) { s = k;  d = kb;            idx = (bid - 8192) * 256 + t; }
    else if (bid < 24576) { s = v;  d = vb;            idx = (bid - 16384) * 256 + t; }
    else if (bid < 25600) { s = Wq; d = Wb;            idx = (bid - 24576) * 256 + t; }
    else if (bid < 26624) { s = Wk; d = Wb + 262144;   idx = (bid - 25600) * 256 + t; }
    else if (bid < 27648) { s = Wv; d = Wb + 524288;   idx = (bid - 26624) * 256 + t; }
    else {
        for (int i = t; i < 3072; i += 256)
            biasCat[i] = (i < 1024) ? bq[i] : (i < 2048) ? bk[i - 1024] : bv[i - 2048];
        return;
    }
    float4 vv = s[idx];
    ushort4 o;
    o.x = f2b(vv.x); o.y = f2b(vv.y); o.z = f2b(vv.z); o.w = f2b(vv.w);
    d[idx] = o;
}

// ===========================================================================
// 256xBN TN GEMM (T2 st_16x32 2-bit swizzle + counted vmcnt + T5 setprio).
// BK=64, 512 threads = 8 waves (2M x 4N), per-wave 128 x BN/4.
// LDS: A[2buf][2half][128][64] (64 KiB) | B[2buf][2half][BN/2][64].
//
// Swizzle (involution, both sides): physical byte = logical ^ ((logical>>9)&3)<<5.
//   stage: granule cl = tid ^ ((tid>>4)&6) (bits 5-6 of granule byte -> bits 1-2
//   of granule index); read: elem XOR axr = ((row>>2)&3)<<4, row bits from
//   lane&15 only (wr*64 / wc*16 / wc*32 / mi2*16 / ni2*16 are 0 mod 4 in row>>2&3).
//   Spreads each read's 4 row-quads over byte-cols {0,32,64,96} -> all 32 banks,
//   8 dword-accesses/bank = conflict-free minimum.
//
// BN=256 (attn): proven 4-phase schedule, boundary vmcnt(4), 9 barriers/tile.
// BN=128 (proj/out): merged 2-phase, ONE barrier per phase:
//   P1: {vmcnt(6); bar} read A-h0,B-g0,B-g1 | stage A-h1(T+1)->nxt | lgkm0 |
//       prio 16xMFMA (acc rows 0-3, both col halves)
//   P2: {vmcnt(6); bar} read A-h1            | stage G1(T+2)->cur  | lgkm0 |
//       prio 16xMFMA (acc rows 4-7)
//   G1 = {A-h0(2 GLL), B-g0(1), B-g1(1)}; A-h1 = 2 GLL.
//   vmcnt proof (per-wave issue order ... A-h1(T)@P1(T-1), G1(T+1)@P2(T-1),
//   A-h1(T+1)@P1(T), G1(T+2)@P2(T) ...):
//     P1(T) needs G1(T): newest-6 = {G1(T+1)4, A-h1(T)2} -> vmcnt(6).
//     P2(T) needs A-h1(T): newest-6 = {A-h1(T+1)2, G1(T+1)4} -> vmcnt(6).
//     Tail: P1(nt-1) -> vmcnt(2), P2(nt-1) -> vmcnt(0).
//   Region safety: each staged region's last reader retired at its lgkm0 in
//   an earlier phase; the staging wave issues only after the phase-start
//   barrier that follows that lgkm0.
//
// EPI: 0 = dual write fp32 direct + bf16 LDS-coalesced (attn; BN=256);
//      1 = exp(acc+bias)->bf16 LDS-coalesced (proj; BN=128, z==2 -> Calt);
//      2 = fp32 only, direct (out; BN=128).
// ===========================================================================
template<int EPI, int BN>
__global__ __launch_bounds__(512, 2) void gemm256(
    const u16* __restrict__ Ap, const u16* __restrict__ Bp,
    float* __restrict__ C32, u16* __restrict__ C16, u16* __restrict__ Calt,
    const float* __restrict__ bias,
    int N, int K, long long sA, long long sB, long long sC)
{
    constexpr int NB2 = BN / 128;              // B frags per half per wave
    constexpr int BH  = BN * 32;               // B half elems (8192 / 4096)
    constexpr int LDSN = 32768 + 4 * BH;       // u16 elems
    __shared__ __align__(16) u16 lds[LDSN];

    const int tid  = threadIdx.x;
    const int lane = tid & 63;
    const int w    = tid >> 6;
    const int wr   = w >> 2, wc = w & 3;       // 2 x 4 waves

    // XCD swizzle within z-plane (tot divisible by 8)
    const int gx  = gridDim.x;
    const int tot = gx * gridDim.y;
    const int lin = blockIdx.y * gx + blockIdx.x;
    const int vlin = (lin & 7) * (tot >> 3) + (lin >> 3);
    const int bx = vlin % gx, by = vlin / gx;
    const int m0 = by * 256, n0 = bx * BN;
    const int z  = blockIdx.z;

    const u16* Ag = Ap + (size_t)z * sA;
    const u16* Bg = Bp + (size_t)z * sB;

    // staging constants: granule c=tid (+512 for 2nd load); logical granule
    // cl = tid ^ ((tid>>4)&6)  [2-bit st_16x32: byte bits 9-10 -> flip bits 5-6]
    const int cl = tid ^ ((tid >> 4) & 6);
    const int lr = cl >> 3;                    // local row 0..63
    const int ce = (cl & 7) * 8;               // col element
    const int arow = m0 + lr;                  // + h*64 ; 2nd load +128
    const int brow = (BN == 256) ? (n0 + (lr & 31) + ((lr & 32) << 1))
                                 : (n0 + lr);  // + g*(BN/8)

    // frag-read constants (element offsets within a half)
    const int axr = ((lane >> 2) & 3) << 4;    // read-side 2-bit swizzle XOR
    const int ar0 = (wr * 64 + (lane & 15)) * 64 + (lane >> 4) * 8;
    const int br0 = (BN == 256)
        ? ((wc * 32 + (lane & 15)) * 64 + (lane >> 4) * 8)
        : ((wc * 16 + (lane & 15)) * 64 + (lane >> 4) * 8);

#define GLL16(gsrc, ldsoff)                                                    \
    __builtin_amdgcn_global_load_lds(                                          \
        (__attribute__((address_space(1))) void*)(uintptr_t)(gsrc),            \
        (__attribute__((address_space(3))) void*)&lds[ldsoff], 16, 0, 0)

#define STAGE_A(c, h, T)                                                       \
    do { const u16* _s = Ag + (size_t)(arow + (h) * 64) * K + (T) * 64 + ce;   \
         int _d = (((c) << 1) + (h)) * 8192 + tid * 8;                         \
         GLL16(_s, _d); GLL16(_s + (size_t)128 * K, _d + 4096); } while (0)

#define STAGE_B(c, g, T)                                                       \
    do { if constexpr (BN == 256) {                                            \
             const u16* _s = Bg + (size_t)(brow + (g) * 32) * K + (T) * 64 + ce; \
             int _d = 32768 + (((c) << 1) + (g)) * 8192 + tid * 8;             \
             GLL16(_s, _d); GLL16(_s + (size_t)128 * K, _d + 4096);            \
         } else {                                                              \
             const u16* _s = Bg + (size_t)(brow + (g) * 64) * K + (T) * 64 + ce; \
             int _d = 32768 + (((c) << 1) + (g)) * 4096 + tid * 8;             \
             GLL16(_s, _d);                                                    \
         } } while (0)

#define SBAR asm volatile("s_barrier" ::: "memory")
#define LGKM0 do { asm volatile("s_waitcnt lgkmcnt(0)" ::: "memory");          \
                   __builtin_amdgcn_sched_barrier(0); } while (0)

#define LDA(base)                                                              \
    _Pragma("unroll") for (int mi2 = 0; mi2 < 4; ++mi2)                        \
    _Pragma("unroll") for (int ks = 0; ks < 2; ++ks)                           \
        afr[mi2][ks] = __builtin_bit_cast(bf16x8,                              \
            *(const i32x4*)&lds[(base) + ((ar0 + mi2 * 1024 + ks * 32) ^ axr)]);

#define LDB(dst, base)                                                         \
    _Pragma("unroll") for (int ni2 = 0; ni2 < NB2; ++ni2)                      \
    _Pragma("unroll") for (int ks = 0; ks < 2; ++ks)                           \
        dst[ni2][ks] = __builtin_bit_cast(bf16x8,                              \
            *(const i32x4*)&lds[(base) + ((br0 + ni2 * 1024 + ks * 32) ^ axr)]);

#define MFMA_Q(mb, nb, bfrag)                                                  \
    __builtin_amdgcn_s_setprio(1);                                             \
    _Pragma("unroll") for (int mi2 = 0; mi2 < 4; ++mi2)                        \
    _Pragma("unroll") for (int ni2 = 0; ni2 < NB2; ++ni2)                      \
    _Pragma("unroll") for (int ks = 0; ks < 2; ++ks)                           \
        acc[(mb) + mi2][(nb) + ni2] = __builtin_amdgcn_mfma_f32_16x16x32_bf16( \
            afr[mi2][ks], bfrag[ni2][ks], acc[(mb) + mi2][(nb) + ni2], 0, 0, 0); \
    __builtin_amdgcn_s_setprio(0)

    f32x4 acc[8][2 * NB2];
#pragma unroll
    for (int i = 0; i < 8; ++i)
#pragma unroll
        for (int j = 0; j < 2 * NB2; ++j) acc[i][j] = (f32x4)0.0f;

    bf16x8 afr[4][2], b0f[NB2][2], b1f[NB2][2];

    const int nt = K >> 6;

    if constexpr (BN == 256) {
        // -------- proven 4-phase schedule (attn) --------
        STAGE_A(0, 0, 0); STAGE_B(0, 0, 0);
        STAGE_A(0, 1, 0); STAGE_B(0, 1, 0);
        STAGE_A(1, 0, 1); STAGE_B(1, 0, 1);

        for (int T = 0; T < nt; ++T) {
            const int cur = T & 1, nxt = cur ^ 1;
            const int ab = (cur << 1) * 8192;
            const int bb = 32768 + (cur << 1) * BH;

            if (T + 1 < nt) asm volatile("s_waitcnt vmcnt(4)" ::: "memory");
            else            asm volatile("s_waitcnt vmcnt(0)" ::: "memory");
            SBAR;
            LDA(ab); LDB(b0f, bb);
            if (T + 1 < nt) STAGE_B(nxt, 1, T + 1);
            SBAR; LGKM0;
            MFMA_Q(0, 0, b0f);
            SBAR;
            LDB(b1f, bb + BH);
            if (T + 1 < nt) STAGE_A(nxt, 1, T + 1);
            SBAR; LGKM0;
            MFMA_Q(0, NB2, b1f);
            SBAR;
            LDA(ab + 8192);
            if (T + 2 < nt) STAGE_A(cur, 0, T + 2);
            SBAR; LGKM0;
            MFMA_Q(4, 0, b0f);
            SBAR;
            if (T + 2 < nt) STAGE_B(cur, 0, T + 2);
            SBAR; LGKM0;
            MFMA_Q(4, NB2, b1f);
            SBAR;
        }
    } else {
        // -------- merged 2-phase schedule (proj/out) --------
        // prologue issue order (per wave): G1(0), A-h1(0), G1(1)
        STAGE_A(0, 0, 0); STAGE_B(0, 0, 0); STAGE_B(0, 1, 0);   // G1(0)->buf0
        STAGE_A(0, 1, 0);                                        // A-h1(0)->buf0
        STAGE_A(1, 0, 1); STAGE_B(1, 0, 1); STAGE_B(1, 1, 1);   // G1(1)->buf1

        for (int T = 0; T < nt; ++T) {
            const int cur = T & 1, nxt = cur ^ 1;
            const int ab = (cur << 1) * 8192;
            const int bb = 32768 + (cur << 1) * BH;

            // ---- P1 ----
            if (T + 1 < nt) asm volatile("s_waitcnt vmcnt(6)" ::: "memory");
            else            asm volatile("s_waitcnt vmcnt(2)" ::: "memory");
            SBAR;
            LDA(ab); LDB(b0f, bb); LDB(b1f, bb + BH);
            if (T + 1 < nt) STAGE_A(nxt, 1, T + 1);
            LGKM0;
            MFMA_Q(0, 0, b0f); MFMA_Q(0, 1, b1f);

            // ---- P2 ----
            if (T + 1 < nt) asm volatile("s_waitcnt vmcnt(6)" ::: "memory");
            else            asm volatile("s_waitcnt vmcnt(0)" ::: "memory");
            SBAR;
            LDA(ab + 8192);
            if (T + 2 < nt) { STAGE_A(cur, 0, T + 2); STAGE_B(cur, 0, T + 2);
                              STAGE_B(cur, 1, T + 2); }
            LGKM0;
            MFMA_Q(4, 0, b0f); MFMA_Q(4, 1, b1f);
        }
    }

    // ------------------------------------------------------------------
    // Epilogue. C row = m0 + wr*128 + mi*16 + (lane>>4)*4 + j.
    // BN=256 col = n0 + wc*64 + ni*16 + (lane&15)   (ni 0..3)
    // BN=128 col = n0 + ni*64 + wc*16 + (lane&15)   (ni 0..1)
    // bf16 outputs staged through LDS with col XOR ((row>>2)&3)<<4
    // (bank-quad separation of the 4 row-groups), emitted as dwordx4.
    // ------------------------------------------------------------------
    const int cr0 = m0 + wr * 128 + ((lane >> 4) << 2);

    if constexpr (EPI == 0) {                 // attn: fp32 direct + bf16 via LDS
        const int cc0 = n0 + wc * 64 + (lane & 15);
        float* Cg = C32 + (size_t)z * sC;
#pragma unroll
        for (int mi = 0; mi < 8; ++mi)
#pragma unroll
            for (int ni = 0; ni < 4; ++ni)
#pragma unroll
                for (int j = 0; j < 4; ++j)
                    Cg[(size_t)(cr0 + mi * 16 + j) * N + cc0 + ni * 16] = acc[mi][ni][j];

        u16* sE = lds;                         // [128][264] u16
        u16* Cb = C16 + (size_t)z * sC;
        const int wrow0 = ((lane >> 4) << 2);
        const int wcol0 = wc * 64 + (lane & 15);
        const int rr = tid >> 2;
        const int c0 = (tid & 3) * 8;
        const int rxor = ((rr >> 2) & 3) << 4;
        __syncthreads();                       // LDS free (loop fully drained)
#pragma unroll
        for (int p = 0; p < 2; ++p) {
            if (wr == p) {
#pragma unroll
                for (int mi = 0; mi < 8; ++mi)
#pragma unroll
                    for (int j = 0; j < 4; ++j) {
                        int row = wrow0 + mi * 16 + j;
                        int cx = ((row >> 2) & 3) << 4;
#pragma unroll
                        for (int ni = 0; ni < 4; ++ni)
                            sE[row * 264 + ((wcol0 + ni * 16) ^ cx)] =
                                f2b(acc[mi][ni][j]);
                    }
            }
            __syncthreads();
#pragma unroll
            for (int i = 0; i < 8; ++i) {
                i32x4 vv = *(const i32x4*)&sE[rr * 264 + ((c0 + i * 32) ^ rxor)];
                *(i32x4*)&Cb[(size_t)(m0 + p * 128 + rr) * N + n0 + c0 + i * 32] = vv;
            }
            if (p == 0) __syncthreads();
        }
    } else if constexpr (EPI == 1) {          // proj (BN=128): exp+bias -> bf16
        u16* sE = lds;                         // [128][136] u16
        u16* Cb = (z == 2) ? Calt : (C16 + (size_t)z * sC);
        const int colb = wc * 16 + (lane & 15);
        const float bv0 = bias[(size_t)z * 1024 + n0 + colb];
        const float bv1 = bias[(size_t)z * 1024 + n0 + 64 + colb];
        const int wrow0 = ((lane >> 4) << 2);
        const int rr = tid >> 2, t4 = tid & 3;
        const int rxor = ((rr >> 2) & 3) << 4;
        __syncthreads();
#pragma unroll
        for (int p = 0; p < 2; ++p) {
            if (wr == p) {
#pragma unroll
                for (int mi = 0; mi < 8; ++mi)
#pragma unroll
                    for (int j = 0; j < 4; ++j) {
                        int row = wrow0 + mi * 16 + j;
                        int cx = ((row >> 2) & 3) << 4;
                        sE[row * 136 + (colb ^ cx)]        = f2b(__expf(acc[mi][0][j] + bv0));
                        sE[row * 136 + ((64 + colb) ^ cx)] = f2b(__expf(acc[mi][1][j] + bv1));
                    }
            }
            __syncthreads();
#pragma unroll
            for (int i = 0; i < 4; ++i) {
                i32x4 vv = *(const i32x4*)&sE[rr * 136 + (((t4 + i * 4) * 8) ^ rxor)];
                *(i32x4*)&Cb[(size_t)(m0 + p * 128 + rr) * N + n0 + (t4 + i * 4) * 8] = vv;
            }
            if (p == 0) __syncthreads();
        }
    } else {                                   // out (BN=128): fp32 direct
        float* Cg = C32 + (size_t)z * sC;
        const int colb = wc * 16 + (lane & 15);
#pragma unroll
        for (int mi = 0; mi < 8; ++mi)
#pragma unroll
            for (int ni = 0; ni < 2; ++ni)
#pragma unroll
                for (int j = 0; j < 4; ++j)
                    Cg[(size_t)(cr0 + mi * 16 + j) * N + n0 + ni * 64 + colb] =
                        acc[mi][ni][j];
    }
#undef GLL16
#undef STAGE_A
#undef STAGE_B
#undef SBAR
#undef LGKM0
#undef LDA
#undef LDB
#undef MFMA_Q
}

// ---- fused: row softmax (qE) + column partials (kE, vE) --------------------
__global__ __launch_bounds__(256) void sm_partials(
    u16* __restrict__ qE, const u16* __restrict__ kE, const u16* __restrict__ vE,
    float* __restrict__ kpart, float* __restrict__ vpart)
{
    int bid = blockIdx.x, t = threadIdx.x;
    if (bid < 8192) {                          // row softmax over D=1024
        u16* p = qE + (size_t)bid * 1024;
        ushort4 v = *(ushort4*)&p[t * 4];
        float e0 = b2f(v.x), e1 = b2f(v.y), e2 = b2f(v.z), e3 = b2f(v.w);
        float s = (e0 + e1) + (e2 + e3);
#pragma unroll
        for (int off = 32; off; off >>= 1) s += __shfl_down(s, off);
        __shared__ float red[4];
        if ((t & 63) == 0) red[t >> 6] = s;
        __syncthreads();
        float inv = 1.0f / ((red[0] + red[1]) + (red[2] + red[3]));
        ushort4 o;
        o.x = f2b(e0 * inv); o.y = f2b(e1 * inv);
        o.z = f2b(e2 * inv); o.w = f2b(e3 * inv);
        *(ushort4*)&p[t * 4] = o;
    } else {                                   // column partials, 128-row chunks
        int j = bid - 8192;
        const u16* d; float* part;
        if (j < 64) { d = kE; part = kpart; } else { d = vE; part = vpart; j -= 64; }
        int b = j >> 4, c = j & 15;
        const u16* base = d + ((size_t)b * 2048 + c * 128) * 1024 + t * 4;
        float a0 = 0, a1 = 0, a2 = 0, a3 = 0;
        for (int s = 0; s < 128; ++s) {
            ushort4 v = *(const ushort4*)(base + (size_t)s * 1024);
            a0 += b2f(v.x); a1 += b2f(v.y); a2 += b2f(v.z); a3 += b2f(v.w);
        }
        *(float4*)(part + ((size_t)(b * 16 + c)) * 1024 + t * 4) = make_float4(a0, a1, a2, a3);
    }
}

// ---- fused: reduce partials -> kinv, vinv ---------------------------------
__global__ __launch_bounds__(256) void col_reduce2(
    const float* __restrict__ kpart, const float* __restrict__ vpart,
    float* __restrict__ kinv, float* __restrict__ vinv)
{
    int bid = blockIdx.x;
    const float* part; float* inv; float mult;
    if (bid < 16) { part = kpart; inv = kinv; mult = 0.03125f; }
    else          { part = vpart; inv = vinv; mult = 1.0f; bid -= 16; }
    int idx = bid * 256 + threadIdx.x;         // 0..4095 over (b,e)
    int b = idx >> 10, e = idx & 1023;
    float s = 0;
    for (int c = 0; c < 16; ++c) s += part[((size_t)(b * 16 + c)) * 1024 + e];
    inv[idx] = mult / s;
}

// ---- fused: kp in-place col-norm + vp normalize+transpose ------------------
__global__ __launch_bounds__(256) void norm_all(
    u16* __restrict__ kE, const float* __restrict__ kinv,
    const u16* __restrict__ vE, const float* __restrict__ vinv,
    u16* __restrict__ vpT)
{
    int bid = blockIdx.x, t = threadIdx.x;
    if (bid < 8192) {                          // col_norm on kE
        int b = bid >> 11, s = bid & 2047;
        u16* p = kE + ((size_t)b * 2048 + s) * 1024 + t * 4;
        float4 iv = *(const float4*)(kinv + b * 1024 + t * 4);
        ushort4 v = *(ushort4*)p;
        v.x = f2b(b2f(v.x) * iv.x); v.y = f2b(b2f(v.y) * iv.y);
        v.z = f2b(b2f(v.z) * iv.z); v.w = f2b(b2f(v.w) * iv.w);
        *(ushort4*)p = v;
    } else {                                   // transpose+norm vE -> vpT
        __shared__ __align__(16) u16 tile[64][68];
        int j = bid - 8192;
        int b = j >> 9, y = (j >> 5) & 15, x = j & 31;
        int s0 = x * 64, e0 = y * 64, t2 = t;
        int lr = t2 >> 4, lc = (t2 & 15) * 4;
#pragma unroll
        for (int i = 0; i < 4; ++i) {
            int sr = i * 16 + lr;
            ushort4 v = *(const ushort4*)(vE + ((size_t)b * 2048 + s0 + sr) * 1024 + e0 + lc);
            tile[sr][lc] = v.x; tile[sr][lc + 1] = v.y;
            tile[sr][lc + 2] = v.z; tile[sr][lc + 3] = v.w;
        }
        __syncthreads();
#pragma unroll
        for (int i = 0; i < 4; ++i) {
            int er = i * 16 + lr;
            float iv = vinv[b * 1024 + e0 + er];
            ushort4 v;
            v.x = f2b(b2f(tile[lc + 0][er]) * iv);
            v.y = f2b(b2f(tile[lc + 1][er]) * iv);
            v.z = f2b(b2f(tile[lc + 2][er]) * iv);
            v.w = f2b(b2f(tile[lc + 3][er]) * iv);
            *(ushort4*)(vpT + ((size_t)b * 1024 + e0 + er) * 2048 + s0 + lc) = v;
        }
    }
}

extern "C" void kernel_launch(void* const* d_in, const int* in_sizes, int n_in,
                              void* d_out, int out_size, void* d_ws, size_t ws_size,
                              hipStream_t stream)
{
    const float* q  = (const float*)d_in[0];
    const float* k  = (const float*)d_in[1];
    const float* v  = (const float*)d_in[2];
    const float* Wq = (const float*)d_in[3];
    const float* bq = (const float*)d_in[4];
    const float* Wk = (const float*)d_in[5];
    const float* bk = (const float*)d_in[6];
    const float* Wv = (const float*)d_in[7];
    const float* bv = (const float*)d_in[8];

    float* out  = (float*)d_out;          // [4,2048,1024] fp32
    float* attn = out + 8388608;          // [4,2048,2048] fp32

    u16* wsU = (u16*)d_ws;
    u16* qE   = wsU;                      // R0: exp'd q logits -> qp
    u16* kE   = wsU + 8388608;            // R1: exp'd k logits -> kp
    u16* Wb   = wsU + 16777216;           // R2: Wqb|Wkb|Wvb (stride 1M)
    u16* qb   = wsU + 25165824;           // R3: q bf16 (dead after proj)
    u16* kb   = wsU + 33554432;           // R4: k bf16 (dead after proj)
    u16* vb   = wsU + 41943040;           // R4+8.4M: v bf16 (dead after proj)
    u16* vpT  = wsU + 25165824;           // R3 after proj: vpT [4,1024,2048]
    u16* attnB = wsU + 33554432;          // R4 after proj: attn bf16
    u16* vE   = (u16*)attn;               // d_out attn region as scratch

    float* tail  = (float*)(wsU + 50331648);
    float* kpart = tail;                  // [4,16,1024]
    float* vpart = tail + 65536;
    float* kinv  = tail + 131072;         // [4,1024]
    float* vinv  = tail + 135168;
    float* biasCat = tail + 139264;       // [3,1024] bq|bk|bv

    const long long SD = 2048LL * 1024, SS = 2048LL * 2048, DS = 1024LL * 2048;

    // ---- 1: convert inputs + weights to bf16, gather biases ----
    cvt_all<<<dim3(27649), dim3(256), 0, stream>>>(
        (const float4*)q, (const float4*)k, (const float4*)v,
        (const float4*)Wq, (const float4*)Wk, (const float4*)Wv,
        bq, bk, bv,
        (ushort4*)qb, (ushort4*)kb, (ushort4*)vb, (ushort4*)Wb, biasCat);

    // ---- 2: batched projections (256x128, 2-phase): z=0/1/2 -> qE, kE, vE ----
    gemm256<1, 128><<<dim3(8, 32, 3), dim3(512), 0, stream>>>(
        qb, Wb, nullptr, qE, vE, biasCat,
        1024, 1024, 8388608LL, 1048576LL, 8388608LL);

    // ---- 3: row softmax (qE) + col partials (kE, vE) ----
    sm_partials<<<dim3(8320), dim3(256), 0, stream>>>(qE, kE, vE, kpart, vpart);

    // ---- 4: reduce -> kinv (x 1/32), vinv ----
    col_reduce2<<<dim3(32), dim3(256), 0, stream>>>(kpart, vpart, kinv, vinv);

    // ---- 5: kp col-norm in place + vp normalize+transpose -> vpT ----
    norm_all<<<dim3(10240), dim3(256), 0, stream>>>(kE, kinv, vE, vinv, vpT);

    // ---- 6: attn = qp @ kp^T -> fp32 d_out + bf16 ws copy (256x256) ----
    gemm256<0, 256><<<dim3(8, 8, 4), dim3(512), 0, stream>>>(
        qE, kE, attn, attnB, nullptr, nullptr, 2048, 1024, SD, SD, SS);

    // ---- 7: out = attnB @ vpT^T -> fp32 d_out (256x128, 2-phase) ----
    gemm256<2, 128><<<dim3(8, 8, 4), dim3(512), 0, stream>>>(
        attnB, vpT, out, nullptr, nullptr, nullptr, 1024, 2048, SS, DS, SD);
}

// Round 6
// 221.383 us; speedup vs baseline: 1.3106x; 1.0031x over previous
//
#include <hip/hip_runtime.h>
#include <math.h>

// LinearAttention B=4, S=2048, D=1024 — bf16 MFMA.
// R6: proj/out moved to a 128x128 tile (64 KiB LDS -> 2 blocks/CU, 16 waves/CU)
// with the merged 2-phase counted-vmcnt schedule. R5 analysis showed
// SQ_LDS_BANK_CONFLICT is a fixed ~14cyc per global_load_lds write (counter
// identical across 3 rounds of LDS changes) — the real limiter was 1 block/CU
// (96KB LDS): every boundary stall idled the whole CU. attn keeps 256x256 4-phase.
//   proj: 128x128 2-phase, grid 8x64x3 = 1536 blocks (3 rounds @ 2/CU)
//   attn: 256x256 4-phase, grid 8x8x4  = 256 blocks (1 round @ 1/CU)
//   out : 128x128 2-phase, grid 8x16x4 = 512 blocks (1 round @ 2/CU)
//
// Workspace map (u16 elems):
//   R0 [0,        8388608): qE  (exp'd q logits -> qp bf16)
//   R1 [8388608, 16777216): kE
//   R2 [16777216,25165824): Wqb@+0, Wkb@+1M, Wvb@+2M (dead after proj)
//   R3 [25165824,33554432): qb (dead after proj) -> vpT [4,1024,2048]
//   R4 [33554432,50331648): kb@+0, vb@+8.4M (dead after proj) -> attnB bf16
//   tail @ 50331648 (floats): kpart, vpart, kinv, vinv, biasCat[3][1024]
//   vE lives in d_out's attn region as u16 scratch (dead before attn GEMM writes it).

typedef float  f32x4  __attribute__((ext_vector_type(4)));
typedef __bf16 bf16x8 __attribute__((ext_vector_type(8)));
typedef int    i32x4  __attribute__((ext_vector_type(4)));
typedef unsigned short u16;

__device__ __forceinline__ float b2f(u16 u) {
    unsigned int i = ((unsigned int)u) << 16; float f;
    __builtin_memcpy(&f, &i, 4); return f;
}
__device__ __forceinline__ u16 f2b(float f) {  // round-to-nearest-even
    unsigned int i; __builtin_memcpy(&i, &f, 4);
    i += 0x7FFFu + ((i >> 16) & 1u);
    return (u16)(i >> 16);
}

// ---- mega convert: q,k,v,Wq,Wk,Wv fp32->bf16 + bias gather -----------------
__global__ __launch_bounds__(256) void cvt_all(
    const float4* __restrict__ q, const float4* __restrict__ k,
    const float4* __restrict__ v, const float4* __restrict__ Wq,
    const float4* __restrict__ Wk, const float4* __restrict__ Wv,
    const float* __restrict__ bq, const float* __restrict__ bk,
    const float* __restrict__ bv,
    ushort4* __restrict__ qb, ushort4* __restrict__ kb,
    ushort4* __restrict__ vb, ushort4* __restrict__ Wb,
    float* __restrict__ biasCat)
{
    int bid = blockIdx.x, t = threadIdx.x;
    const float4* s; ushort4* d; int idx;
    if (bid < 8192)       { s = q;  d = qb;            idx = bid * 256 + t; }
    else if (bid < 16384) { s = k;  d = kb;            idx = (bid - 8192) * 256 + t; }
    else if (bid < 24576) { s = v;  d = vb;            idx = (bid - 16384) * 256 + t; }
    else if (bid < 25600) { s = Wq; d = Wb;            idx = (bid - 24576) * 256 + t; }
    else if (bid < 26624) { s = Wk; d = Wb + 262144;   idx = (bid - 25600) * 256 + t; }
    else if (bid < 27648) { s = Wv; d = Wb + 524288;   idx = (bid - 26624) * 256 + t; }
    else {
        for (int i = t; i < 3072; i += 256)
            biasCat[i] = (i < 1024) ? bq[i] : (i < 2048) ? bk[i - 1024] : bv[i - 2048];
        return;
    }
    float4 vv = s[idx];
    ushort4 o;
    o.x = f2b(vv.x); o.y = f2b(vv.y); o.z = f2b(vv.z); o.w = f2b(vv.w);
    d[idx] = o;
}

// ===========================================================================
// 256x256 4-phase TN GEMM (attn only). Unchanged proven schedule.
// ===========================================================================
__global__ __launch_bounds__(512, 2) void gemm256_attn(
    const u16* __restrict__ Ap, const u16* __restrict__ Bp,
    float* __restrict__ C32, u16* __restrict__ C16,
    int N, int K, long long sA, long long sB, long long sC)
{
    __shared__ __align__(16) u16 lds[65536];   // 128 KiB

    const int tid  = threadIdx.x;
    const int lane = tid & 63;
    const int w    = tid >> 6;
    const int wr   = w >> 2, wc = w & 3;

    const int gx  = gridDim.x;
    const int tot = gx * gridDim.y;
    const int lin = blockIdx.y * gx + blockIdx.x;
    const int vlin = (lin & 7) * (tot >> 3) + (lin >> 3);
    const int bx = vlin % gx, by = vlin / gx;
    const int m0 = by * 256, n0 = bx * 256;
    const int z  = blockIdx.z;

    const u16* Ag = Ap + (size_t)z * sA;
    const u16* Bg = Bp + (size_t)z * sB;

    const int cl = tid ^ ((tid >> 4) & 6);
    const int lr = cl >> 3;
    const int ce = (cl & 7) * 8;
    const int arow = m0 + lr;
    const int brow = n0 + (lr & 31) + ((lr & 32) << 1);

    const int axr = ((lane >> 2) & 3) << 4;
    const int ar0 = (wr * 64 + (lane & 15)) * 64 + (lane >> 4) * 8;
    const int br0 = (wc * 32 + (lane & 15)) * 64 + (lane >> 4) * 8;

#define GLL16(gsrc, ldsoff)                                                    \
    __builtin_amdgcn_global_load_lds(                                          \
        (__attribute__((address_space(1))) void*)(uintptr_t)(gsrc),            \
        (__attribute__((address_space(3))) void*)&lds[ldsoff], 16, 0, 0)

#define STAGE_A(c, h, T)                                                       \
    do { const u16* _s = Ag + (size_t)(arow + (h) * 64) * K + (T) * 64 + ce;   \
         int _d = (((c) << 1) + (h)) * 8192 + tid * 8;                         \
         GLL16(_s, _d); GLL16(_s + (size_t)128 * K, _d + 4096); } while (0)

#define STAGE_B(c, g, T)                                                       \
    do { const u16* _s = Bg + (size_t)(brow + (g) * 32) * K + (T) * 64 + ce;   \
         int _d = 32768 + (((c) << 1) + (g)) * 8192 + tid * 8;                 \
         GLL16(_s, _d); GLL16(_s + (size_t)128 * K, _d + 4096); } while (0)

#define SBAR asm volatile("s_barrier" ::: "memory")
#define LGKM0 do { asm volatile("s_waitcnt lgkmcnt(0)" ::: "memory");          \
                   __builtin_amdgcn_sched_barrier(0); } while (0)

#define LDA(base)                                                              \
    _Pragma("unroll") for (int mi2 = 0; mi2 < 4; ++mi2)                        \
    _Pragma("unroll") for (int ks = 0; ks < 2; ++ks)                           \
        afr[mi2][ks] = __builtin_bit_cast(bf16x8,                              \
            *(const i32x4*)&lds[(base) + ((ar0 + mi2 * 1024 + ks * 32) ^ axr)]);

#define LDB(dst, base)                                                         \
    _Pragma("unroll") for (int ni2 = 0; ni2 < 2; ++ni2)                        \
    _Pragma("unroll") for (int ks = 0; ks < 2; ++ks)                           \
        dst[ni2][ks] = __builtin_bit_cast(bf16x8,                              \
            *(const i32x4*)&lds[(base) + ((br0 + ni2 * 1024 + ks * 32) ^ axr)]);

#define MFMA_Q(mb, nb, bfrag)                                                  \
    __builtin_amdgcn_s_setprio(1);                                             \
    _Pragma("unroll") for (int mi2 = 0; mi2 < 4; ++mi2)                        \
    _Pragma("unroll") for (int ni2 = 0; ni2 < 2; ++ni2)                        \
    _Pragma("unroll") for (int ks = 0; ks < 2; ++ks)                           \
        acc[(mb) + mi2][(nb) + ni2] = __builtin_amdgcn_mfma_f32_16x16x32_bf16( \
            afr[mi2][ks], bfrag[ni2][ks], acc[(mb) + mi2][(nb) + ni2], 0, 0, 0); \
    __builtin_amdgcn_s_setprio(0)

    f32x4 acc[8][4];
#pragma unroll
    for (int i = 0; i < 8; ++i)
#pragma unroll
        for (int j = 0; j < 4; ++j) acc[i][j] = (f32x4)0.0f;

    bf16x8 afr[4][2], b0f[2][2], b1f[2][2];

    const int nt = K >> 6;

    STAGE_A(0, 0, 0); STAGE_B(0, 0, 0);
    STAGE_A(0, 1, 0); STAGE_B(0, 1, 0);
    STAGE_A(1, 0, 1); STAGE_B(1, 0, 1);

    for (int T = 0; T < nt; ++T) {
        const int cur = T & 1, nxt = cur ^ 1;
        const int ab = (cur << 1) * 8192;
        const int bb = 32768 + (cur << 1) * 8192;

        if (T + 1 < nt) asm volatile("s_waitcnt vmcnt(4)" ::: "memory");
        else            asm volatile("s_waitcnt vmcnt(0)" ::: "memory");
        SBAR;
        LDA(ab); LDB(b0f, bb);
        if (T + 1 < nt) STAGE_B(nxt, 1, T + 1);
        SBAR; LGKM0;
        MFMA_Q(0, 0, b0f);
        SBAR;
        LDB(b1f, bb + 8192);
        if (T + 1 < nt) STAGE_A(nxt, 1, T + 1);
        SBAR; LGKM0;
        MFMA_Q(0, 2, b1f);
        SBAR;
        LDA(ab + 8192);
        if (T + 2 < nt) STAGE_A(cur, 0, T + 2);
        SBAR; LGKM0;
        MFMA_Q(4, 0, b0f);
        SBAR;
        if (T + 2 < nt) STAGE_B(cur, 0, T + 2);
        SBAR; LGKM0;
        MFMA_Q(4, 2, b1f);
        SBAR;
    }

    // epilogue: fp32 direct + bf16 via LDS two-pass
    const int cr0 = m0 + wr * 128 + ((lane >> 4) << 2);
    const int cc0 = n0 + wc * 64 + (lane & 15);
    float* Cg = C32 + (size_t)z * sC;
#pragma unroll
    for (int mi = 0; mi < 8; ++mi)
#pragma unroll
        for (int ni = 0; ni < 4; ++ni)
#pragma unroll
            for (int j = 0; j < 4; ++j)
                Cg[(size_t)(cr0 + mi * 16 + j) * N + cc0 + ni * 16] = acc[mi][ni][j];

    u16* sE = lds;                         // [128][264] u16
    u16* Cb = C16 + (size_t)z * sC;
    const int wrow0 = ((lane >> 4) << 2);
    const int wcol0 = wc * 64 + (lane & 15);
    const int rr = tid >> 2;
    const int c0 = (tid & 3) * 8;
    __syncthreads();
#pragma unroll
    for (int p = 0; p < 2; ++p) {
        if (wr == p) {
#pragma unroll
            for (int mi = 0; mi < 8; ++mi)
#pragma unroll
                for (int ni = 0; ni < 4; ++ni)
#pragma unroll
                    for (int j = 0; j < 4; ++j)
                        sE[(wrow0 + mi * 16 + j) * 264 + wcol0 + ni * 16] =
                            f2b(acc[mi][ni][j]);
        }
        __syncthreads();
#pragma unroll
        for (int i = 0; i < 8; ++i) {
            i32x4 vv = *(const i32x4*)&sE[rr * 264 + c0 + i * 32];
            *(i32x4*)&Cb[(size_t)(m0 + p * 128 + rr) * N + n0 + c0 + i * 32] = vv;
        }
        if (p == 0) __syncthreads();
    }
#undef GLL16
#undef STAGE_A
#undef STAGE_B
#undef LDA
#undef LDB
#undef MFMA_Q
}

// ===========================================================================
// 128x128 TN GEMM, 2-phase counted-vmcnt, 64 KiB LDS -> 2 blocks/CU.
// BK=64 split into two 32-col halves; 512 threads = 8 waves (2M x 4N),
// per-wave 64x32 = acc[4][2]; 8 MFMA per phase; 1 GLL per thread per stage.
// LDS: A[2buf][2half][128][32] | B same @ +16384 (u16 elems).
// Swizzle (32-col half, row stride 64B): physical byte = logical ^
//   ((logical>>7)&3)<<4. Stage: granule cl = tid ^ ((tid>>3)&3);
//   read: elem XOR exr = ((lane>>1)&3)<<3 (row bits 1-2 from lane&15 only).
// Schedule per K-tile T (cur=T&1), halves H0 = K 0-31, H1 = K 32-63:
//  P1: {vmcnt(4|2); bar} read H0 frags | stage H1(T+1)->nxt | lgkm0 | 8 MFMA
//  P2: {vmcnt(4|0); bar} read H1 frags | stage H0(T+2)->cur | lgkm0 | 8 MFMA
//  vmcnt proof (issue order ...H1(T)@P1(T-1), H0(T+1)@P2(T-1), H1(T+1)@P1(T)...):
//   P1(T) needs H0(T): newer = {H1(T), H0(T+1)} = 4 -> vmcnt(4); tail 2.
//   P2(T) needs H1(T): newer = {H0(T+1), H1(T+1)} = 4 -> vmcnt(4); tail 0.
//  Region safety: region staged at a phase was last ds_read one phase earlier,
//  retired at that phase's lgkm0 before this phase's barrier.
//  Per-element K order identical to previous schedules (bitwise-same output).
// EPI: 1 = exp(acc+bias)->bf16 via LDS single-pass (proj; z==2 -> Calt);
//      2 = fp32 direct (out).
// ===========================================================================
template<int EPI>
__global__ __launch_bounds__(512, 4) void gemm128(
    const u16* __restrict__ Ap, const u16* __restrict__ Bp,
    float* __restrict__ C32, u16* __restrict__ C16, u16* __restrict__ Calt,
    const float* __restrict__ bias,
    int N, int K, long long sA, long long sB, long long sC)
{
    __shared__ __align__(16) u16 lds[32768];   // 64 KiB

    const int tid  = threadIdx.x;
    const int lane = tid & 63;
    const int w    = tid >> 6;
    const int wr   = w >> 2, wc = w & 3;       // 2M x 4N waves

    const int gx  = gridDim.x;
    const int tot = gx * gridDim.y;
    const int lin = blockIdx.y * gx + blockIdx.x;
    const int vlin = (lin & 7) * (tot >> 3) + (lin >> 3);
    const int bx = vlin % gx, by = vlin / gx;
    const int m0 = by * 128, n0 = bx * 128;
    const int z  = blockIdx.z;

    const u16* Ag = Ap + (size_t)z * sA;
    const u16* Bg = Bp + (size_t)z * sB;

    // staging: granule = tid (16B); logical cl = tid ^ ((tid>>3)&3)
    const int cl = tid ^ ((tid >> 3) & 3);
    const int lr = cl >> 2;                    // row 0..127
    const int ce = (cl & 3) * 8;               // col elem 0/8/16/24
    const int arow = m0 + lr, brow = n0 + lr;

    // frag reads: elem XOR exr, frag base = row*32 + (lane>>4)*8
    const int exr = ((lane >> 1) & 3) << 3;
    const int ar0 = (wr * 64 + (lane & 15)) * 32 + (lane >> 4) * 8;
    const int br0 = (wc * 32 + (lane & 15)) * 32 + (lane >> 4) * 8;

#define GLL16(gsrc, ldsoff)                                                    \
    __builtin_amdgcn_global_load_lds(                                          \
        (__attribute__((address_space(1))) void*)(uintptr_t)(gsrc),            \
        (__attribute__((address_space(3))) void*)&lds[ldsoff], 16, 0, 0)

#define STAGE_A(c, h, T)                                                       \
    GLL16(Ag + (size_t)arow * K + (T) * 64 + (h) * 32 + ce,                    \
          (((c) << 1) + (h)) * 4096 + tid * 8)

#define STAGE_B(c, h, T)                                                       \
    GLL16(Bg + (size_t)brow * K + (T) * 64 + (h) * 32 + ce,                    \
          16384 + (((c) << 1) + (h)) * 4096 + tid * 8)

#define LGKM0 do { asm volatile("s_waitcnt lgkmcnt(0)" ::: "memory");          \
                   __builtin_amdgcn_sched_barrier(0); } while (0)

#define LDAB(base)                                                             \
    _Pragma("unroll") for (int mi2 = 0; mi2 < 4; ++mi2)                        \
        afr[mi2] = __builtin_bit_cast(bf16x8,                                  \
            *(const i32x4*)&lds[(base) + ((ar0 + mi2 * 512) ^ exr)]);          \
    _Pragma("unroll") for (int ni2 = 0; ni2 < 2; ++ni2)                        \
        bfr[ni2] = __builtin_bit_cast(bf16x8,                                  \
            *(const i32x4*)&lds[16384 + (base) + ((br0 + ni2 * 512) ^ exr)]);

#define MFMA8                                                                  \
    __builtin_amdgcn_s_setprio(1);                                             \
    _Pragma("unroll") for (int mi2 = 0; mi2 < 4; ++mi2)                        \
    _Pragma("unroll") for (int ni2 = 0; ni2 < 2; ++ni2)                        \
        acc[mi2][ni2] = __builtin_amdgcn_mfma_f32_16x16x32_bf16(               \
            afr[mi2], bfr[ni2], acc[mi2][ni2], 0, 0, 0);                       \
    __builtin_amdgcn_s_setprio(0)

    f32x4 acc[4][2];
#pragma unroll
    for (int i = 0; i < 4; ++i)
#pragma unroll
        for (int j = 0; j < 2; ++j) acc[i][j] = (f32x4)0.0f;

    bf16x8 afr[4], bfr[2];

    const int nt = K >> 6;

    // prologue: H0(0), H1(0) -> buf0; H0(1) -> buf1
    STAGE_A(0, 0, 0); STAGE_B(0, 0, 0);
    STAGE_A(0, 1, 0); STAGE_B(0, 1, 0);
    STAGE_A(1, 0, 1); STAGE_B(1, 0, 1);

    for (int T = 0; T < nt; ++T) {
        const int cur = T & 1, nxt = cur ^ 1;
        const int ab = (cur << 1) * 4096;

        // ---- P1: K 0-31 ----
        if (T + 1 < nt) asm volatile("s_waitcnt vmcnt(4)" ::: "memory");
        else            asm volatile("s_waitcnt vmcnt(2)" ::: "memory");
        asm volatile("s_barrier" ::: "memory");
        LDAB(ab);
        if (T + 1 < nt) { STAGE_A(nxt, 1, T + 1); STAGE_B(nxt, 1, T + 1); }
        LGKM0;
        MFMA8;

        // ---- P2: K 32-63 ----
        if (T + 1 < nt) asm volatile("s_waitcnt vmcnt(4)" ::: "memory");
        else            asm volatile("s_waitcnt vmcnt(0)" ::: "memory");
        asm volatile("s_barrier" ::: "memory");
        LDAB(ab + 4096);
        if (T + 2 < nt) { STAGE_A(cur, 0, T + 2); STAGE_B(cur, 0, T + 2); }
        LGKM0;
        MFMA8;
    }

    // ---- epilogue ----
    // C row = m0 + wr*64 + mi*16 + (lane>>4)*4 + j; col = n0 + wc*32 + ni*16 + (lane&15)
    if constexpr (EPI == 1) {                  // exp+bias -> bf16, LDS single-pass
        u16* sE = lds;                         // [128][136] u16 (34.8 KB)
        u16* Cb = (z == 2) ? Calt : (C16 + (size_t)z * sC);
        const int colb = wc * 32 + (lane & 15);
        float bv0 = bias[(size_t)z * 1024 + n0 + colb];
        float bv1 = bias[(size_t)z * 1024 + n0 + colb + 16];
        const int wrow0 = wr * 64 + ((lane >> 4) << 2);
        __syncthreads();                       // loop drained (vmcnt0 + lgkm0)
#pragma unroll
        for (int mi = 0; mi < 4; ++mi)
#pragma unroll
            for (int j = 0; j < 4; ++j) {
                int row = wrow0 + mi * 16 + j;
                sE[row * 136 + colb]      = f2b(__expf(acc[mi][0][j] + bv0));
                sE[row * 136 + colb + 16] = f2b(__expf(acc[mi][1][j] + bv1));
            }
        __syncthreads();
        const int rr = tid >> 2, c0 = (tid & 3) * 8;
#pragma unroll
        for (int i = 0; i < 4; ++i) {
            i32x4 vv = *(const i32x4*)&sE[rr * 136 + c0 + i * 32];
            *(i32x4*)&Cb[(size_t)(m0 + rr) * N + n0 + c0 + i * 32] = vv;
        }
    } else {                                   // fp32 direct
        float* Cg = C32 + (size_t)z * sC;
        const int cr0 = m0 + wr * 64 + ((lane >> 4) << 2);
        const int cc0 = n0 + wc * 32 + (lane & 15);
#pragma unroll
        for (int mi = 0; mi < 4; ++mi)
#pragma unroll
            for (int ni = 0; ni < 2; ++ni)
#pragma unroll
                for (int j = 0; j < 4; ++j)
                    Cg[(size_t)(cr0 + mi * 16 + j) * N + cc0 + ni * 16] =
                        acc[mi][ni][j];
    }
#undef GLL16
#undef STAGE_A
#undef STAGE_B
#undef LGKM0
#undef LDAB
#undef MFMA8
}

// ---- fused: row softmax (qE) + column partials (kE, vE) --------------------
__global__ __launch_bounds__(256) void sm_partials(
    u16* __restrict__ qE, const u16* __restrict__ kE, const u16* __restrict__ vE,
    float* __restrict__ kpart, float* __restrict__ vpart)
{
    int bid = blockIdx.x, t = threadIdx.x;
    if (bid < 8192) {                          // row softmax over D=1024
        u16* p = qE + (size_t)bid * 1024;
        ushort4 v = *(ushort4*)&p[t * 4];
        float e0 = b2f(v.x), e1 = b2f(v.y), e2 = b2f(v.z), e3 = b2f(v.w);
        float s = (e0 + e1) + (e2 + e3);
#pragma unroll
        for (int off = 32; off; off >>= 1) s += __shfl_down(s, off);
        __shared__ float red[4];
        if ((t & 63) == 0) red[t >> 6] = s;
        __syncthreads();
        float inv = 1.0f / ((red[0] + red[1]) + (red[2] + red[3]));
        ushort4 o;
        o.x = f2b(e0 * inv); o.y = f2b(e1 * inv);
        o.z = f2b(e2 * inv); o.w = f2b(e3 * inv);
        *(ushort4*)&p[t * 4] = o;
    } else {                                   // column partials, 128-row chunks
        int j = bid - 8192;
        const u16* d; float* part;
        if (j < 64) { d = kE; part = kpart; } else { d = vE; part = vpart; j -= 64; }
        int b = j >> 4, c = j & 15;
        const u16* base = d + ((size_t)b * 2048 + c * 128) * 1024 + t * 4;
        float a0 = 0, a1 = 0, a2 = 0, a3 = 0;
        for (int s = 0; s < 128; ++s) {
            ushort4 v = *(const ushort4*)(base + (size_t)s * 1024);
            a0 += b2f(v.x); a1 += b2f(v.y); a2 += b2f(v.z); a3 += b2f(v.w);
        }
        *(float4*)(part + ((size_t)(b * 16 + c)) * 1024 + t * 4) = make_float4(a0, a1, a2, a3);
    }
}

// ---- fused: reduce partials -> kinv, vinv ---------------------------------
__global__ __launch_bounds__(256) void col_reduce2(
    const float* __restrict__ kpart, const float* __restrict__ vpart,
    float* __restrict__ kinv, float* __restrict__ vinv)
{
    int bid = blockIdx.x;
    const float* part; float* inv; float mult;
    if (bid < 16) { part = kpart; inv = kinv; mult = 0.03125f; }
    else          { part = vpart; inv = vinv; mult = 1.0f; bid -= 16; }
    int idx = bid * 256 + threadIdx.x;         // 0..4095 over (b,e)
    int b = idx >> 10, e = idx & 1023;
    float s = 0;
    for (int c = 0; c < 16; ++c) s += part[((size_t)(b * 16 + c)) * 1024 + e];
    inv[idx] = mult / s;
}

// ---- fused: kp in-place col-norm + vp normalize+transpose ------------------
__global__ __launch_bounds__(256) void norm_all(
    u16* __restrict__ kE, const float* __restrict__ kinv,
    const u16* __restrict__ vE, const float* __restrict__ vinv,
    u16* __restrict__ vpT)
{
    int bid = blockIdx.x, t = threadIdx.x;
    if (bid < 8192) {                          // col_norm on kE
        int b = bid >> 11, s = bid & 2047;
        u16* p = kE + ((size_t)b * 2048 + s) * 1024 + t * 4;
        float4 iv = *(const float4*)(kinv + b * 1024 + t * 4);
        ushort4 v = *(ushort4*)p;
        v.x = f2b(b2f(v.x) * iv.x); v.y = f2b(b2f(v.y) * iv.y);
        v.z = f2b(b2f(v.z) * iv.z); v.w = f2b(b2f(v.w) * iv.w);
        *(ushort4*)p = v;
    } else {                                   // transpose+norm vE -> vpT
        __shared__ __align__(16) u16 tile[64][68];
        int j = bid - 8192;
        int b = j >> 9, y = (j >> 5) & 15, x = j & 31;
        int s0 = x * 64, e0 = y * 64;
        int lr = t >> 4, lc = (t & 15) * 4;
#pragma unroll
        for (int i = 0; i < 4; ++i) {
            int sr = i * 16 + lr;
            ushort4 v = *(const ushort4*)(vE + ((size_t)b * 2048 + s0 + sr) * 1024 + e0 + lc);
            tile[sr][lc] = v.x; tile[sr][lc + 1] = v.y;
            tile[sr][lc + 2] = v.z; tile[sr][lc + 3] = v.w;
        }
        __syncthreads();
#pragma unroll
        for (int i = 0; i < 4; ++i) {
            int er = i * 16 + lr;
            float iv = vinv[b * 1024 + e0 + er];
            ushort4 v;
            v.x = f2b(b2f(tile[lc + 0][er]) * iv);
            v.y = f2b(b2f(tile[lc + 1][er]) * iv);
            v.z = f2b(b2f(tile[lc + 2][er]) * iv);
            v.w = f2b(b2f(tile[lc + 3][er]) * iv);
            *(ushort4*)(vpT + ((size_t)b * 1024 + e0 + er) * 2048 + s0 + lc) = v;
        }
    }
}

extern "C" void kernel_launch(void* const* d_in, const int* in_sizes, int n_in,
                              void* d_out, int out_size, void* d_ws, size_t ws_size,
                              hipStream_t stream)
{
    const float* q  = (const float*)d_in[0];
    const float* k  = (const float*)d_in[1];
    const float* v  = (const float*)d_in[2];
    const float* Wq = (const float*)d_in[3];
    const float* bq = (const float*)d_in[4];
    const float* Wk = (const float*)d_in[5];
    const float* bk = (const float*)d_in[6];
    const float* Wv = (const float*)d_in[7];
    const float* bv = (const float*)d_in[8];

    float* out  = (float*)d_out;          // [4,2048,1024] fp32
    float* attn = out + 8388608;          // [4,2048,2048] fp32

    u16* wsU = (u16*)d_ws;
    u16* qE   = wsU;                      // R0: exp'd q logits -> qp
    u16* kE   = wsU + 8388608;            // R1: exp'd k logits -> kp
    u16* Wb   = wsU + 16777216;           // R2: Wqb|Wkb|Wvb (stride 1M)
    u16* qb   = wsU + 25165824;           // R3: q bf16 (dead after proj)
    u16* kb   = wsU + 33554432;           // R4: k bf16 (dead after proj)
    u16* vb   = wsU + 41943040;           // R4+8.4M: v bf16 (dead after proj)
    u16* vpT  = wsU + 25165824;           // R3 after proj: vpT [4,1024,2048]
    u16* attnB = wsU + 33554432;          // R4 after proj: attn bf16
    u16* vE   = (u16*)attn;               // d_out attn region as scratch

    float* tail  = (float*)(wsU + 50331648);
    float* kpart = tail;                  // [4,16,1024]
    float* vpart = tail + 65536;
    float* kinv  = tail + 131072;         // [4,1024]
    float* vinv  = tail + 135168;
    float* biasCat = tail + 139264;       // [3,1024] bq|bk|bv

    const long long SD = 2048LL * 1024, SS = 2048LL * 2048, DS = 1024LL * 2048;

    // ---- 1: convert inputs + weights to bf16, gather biases ----
    cvt_all<<<dim3(27649), dim3(256), 0, stream>>>(
        (const float4*)q, (const float4*)k, (const float4*)v,
        (const float4*)Wq, (const float4*)Wk, (const float4*)Wv,
        bq, bk, bv,
        (ushort4*)qb, (ushort4*)kb, (ushort4*)vb, (ushort4*)Wb, biasCat);

    // ---- 2: batched projections (128x128, 2 blk/CU): z=0/1/2 -> qE, kE, vE ----
    gemm128<1><<<dim3(8, 64, 3), dim3(512), 0, stream>>>(
        qb, Wb, nullptr, qE, vE, biasCat,
        1024, 1024, 8388608LL, 1048576LL, 8388608LL);

    // ---- 3: row softmax (qE) + col partials (kE, vE) ----
    sm_partials<<<dim3(8320), dim3(256), 0, stream>>>(qE, kE, vE, kpart, vpart);

    // ---- 4: reduce -> kinv (x 1/32), vinv ----
    col_reduce2<<<dim3(32), dim3(256), 0, stream>>>(kpart, vpart, kinv, vinv);

    // ---- 5: kp col-norm in place + vp normalize+transpose -> vpT ----
    norm_all<<<dim3(10240), dim3(256), 0, stream>>>(kE, kinv, vE, vinv, vpT);

    // ---- 6: attn = qp @ kp^T -> fp32 d_out + bf16 ws copy (256x256) ----
    gemm256_attn<<<dim3(8, 8, 4), dim3(512), 0, stream>>>(
        qE, kE, attn, attnB, 2048, 1024, SD, SD, SS);

    // ---- 7: out = attnB @ vpT^T -> fp32 d_out (128x128, 2 blk/CU) ----
    gemm128<2><<<dim3(8, 16, 4), dim3(512), 0, stream>>>(
        attnB, vpT, out, nullptr, nullptr, nullptr, 1024, 2048, SS, DS, SD);
}

// Round 7
// 215.741 us; speedup vs baseline: 1.3448x; 1.0262x over previous
//
#include <hip/hip_runtime.h>
#include <math.h>

// LinearAttention B=4, S=2048, D=1024 — bf16 MFMA.
// R7: proj/out on gemm_bw — 256 threads / 4 waves (2Mx2N), per-wave 128x64
// (BM=256, proj) or 64x64 (BM=128, out), BK=32, 3-buffer LDS ring, one
// phase per K-tile with counted vmcnt. Rationale: per-wave tile area sets
// LDS-reads-per-MFMA and sync-per-MFMA; R6's 64x32/wave capped at ~29% of
// the 2.5PF MFMA peak (16.1 cyc/SIMD per MFMA), attn's 128x64 runs ~2x.
//   proj: BM=256, grid 8x32x3 = 768 blocks (2/CU, 72KB LDS)
//   attn: 256x256 4-phase (unchanged), grid 8x8x4 = 256 blocks
//   out : BM=128, grid 8x16x4 = 512 blocks (2/CU, 48KB LDS)
//
// Workspace map (u16 elems):
//   R0 [0,        8388608): qE  (exp'd q logits -> qp bf16)
//   R1 [8388608, 16777216): kE
//   R2 [16777216,25165824): Wqb@+0, Wkb@+1M, Wvb@+2M (dead after proj)
//   R3 [25165824,33554432): qb (dead after proj) -> vpT [4,1024,2048]
//   R4 [33554432,50331648): kb@+0, vb@+8.4M (dead after proj) -> attnB bf16
//   tail @ 50331648 (floats): kpart, vpart, kinv, vinv, biasCat[3][1024]
//   vE lives in d_out's attn region as u16 scratch (dead before attn GEMM writes it).

typedef float  f32x4  __attribute__((ext_vector_type(4)));
typedef __bf16 bf16x8 __attribute__((ext_vector_type(8)));
typedef int    i32x4  __attribute__((ext_vector_type(4)));
typedef unsigned short u16;

__device__ __forceinline__ float b2f(u16 u) {
    unsigned int i = ((unsigned int)u) << 16; float f;
    __builtin_memcpy(&f, &i, 4); return f;
}
__device__ __forceinline__ u16 f2b(float f) {  // round-to-nearest-even
    unsigned int i; __builtin_memcpy(&i, &f, 4);
    i += 0x7FFFu + ((i >> 16) & 1u);
    return (u16)(i >> 16);
}

// ---- mega convert: q,k,v,Wq,Wk,Wv fp32->bf16 + bias gather -----------------
__global__ __launch_bounds__(256) void cvt_all(
    const float4* __restrict__ q, const float4* __restrict__ k,
    const float4* __restrict__ v, const float4* __restrict__ Wq,
    const float4* __restrict__ Wk, const float4* __restrict__ Wv,
    const float* __restrict__ bq, const float* __restrict__ bk,
    const float* __restrict__ bv,
    ushort4* __restrict__ qb, ushort4* __restrict__ kb,
    ushort4* __restrict__ vb, ushort4* __restrict__ Wb,
    float* __restrict__ biasCat)
{
    int bid = blockIdx.x, t = threadIdx.x;
    const float4* s; ushort4* d; int idx;
    if (bid < 8192)       { s = q;  d = qb;            idx = bid * 256 + t; }
    else if (bid < 16384) { s = k;  d = kb;            idx = (bid - 8192) * 256 + t; }
    else if (bid < 24576) { s = v;  d = vb;            idx = (bid - 16384) * 256 + t; }
    else if (bid < 25600) { s = Wq; d = Wb;            idx = (bid - 24576) * 256 + t; }
    else if (bid < 26624) { s = Wk; d = Wb + 262144;   idx = (bid - 25600) * 256 + t; }
    else if (bid < 27648) { s = Wv; d = Wb + 524288;   idx = (bid - 26624) * 256 + t; }
    else {
        for (int i = t; i < 3072; i += 256)
            biasCat[i] = (i < 1024) ? bq[i] : (i < 2048) ? bk[i - 1024] : bv[i - 2048];
        return;
    }
    float4 vv = s[idx];
    ushort4 o;
    o.x = f2b(vv.x); o.y = f2b(vv.y); o.z = f2b(vv.z); o.w = f2b(vv.w);
    d[idx] = o;
}

// ===========================================================================
// 256x256 4-phase TN GEMM (attn only). Unchanged proven schedule.
// ===========================================================================
__global__ __launch_bounds__(512, 2) void gemm256_attn(
    const u16* __restrict__ Ap, const u16* __restrict__ Bp,
    float* __restrict__ C32, u16* __restrict__ C16,
    int N, int K, long long sA, long long sB, long long sC)
{
    __shared__ __align__(16) u16 lds[65536];   // 128 KiB

    const int tid  = threadIdx.x;
    const int lane = tid & 63;
    const int w    = tid >> 6;
    const int wr   = w >> 2, wc = w & 3;

    const int gx  = gridDim.x;
    const int tot = gx * gridDim.y;
    const int lin = blockIdx.y * gx + blockIdx.x;
    const int vlin = (lin & 7) * (tot >> 3) + (lin >> 3);
    const int bx = vlin % gx, by = vlin / gx;
    const int m0 = by * 256, n0 = bx * 256;
    const int z  = blockIdx.z;

    const u16* Ag = Ap + (size_t)z * sA;
    const u16* Bg = Bp + (size_t)z * sB;

    const int cl = tid ^ ((tid >> 4) & 6);
    const int lr = cl >> 3;
    const int ce = (cl & 7) * 8;
    const int arow = m0 + lr;
    const int brow = n0 + (lr & 31) + ((lr & 32) << 1);

    const int axr = ((lane >> 2) & 3) << 4;
    const int ar0 = (wr * 64 + (lane & 15)) * 64 + (lane >> 4) * 8;
    const int br0 = (wc * 32 + (lane & 15)) * 64 + (lane >> 4) * 8;

#define GLL16(gsrc, ldsoff)                                                    \
    __builtin_amdgcn_global_load_lds(                                          \
        (__attribute__((address_space(1))) void*)(uintptr_t)(gsrc),            \
        (__attribute__((address_space(3))) void*)&lds[ldsoff], 16, 0, 0)

#define STAGE_A(c, h, T)                                                       \
    do { const u16* _s = Ag + (size_t)(arow + (h) * 64) * K + (T) * 64 + ce;   \
         int _d = (((c) << 1) + (h)) * 8192 + tid * 8;                         \
         GLL16(_s, _d); GLL16(_s + (size_t)128 * K, _d + 4096); } while (0)

#define STAGE_B(c, g, T)                                                       \
    do { const u16* _s = Bg + (size_t)(brow + (g) * 32) * K + (T) * 64 + ce;   \
         int _d = 32768 + (((c) << 1) + (g)) * 8192 + tid * 8;                 \
         GLL16(_s, _d); GLL16(_s + (size_t)128 * K, _d + 4096); } while (0)

#define SBAR asm volatile("s_barrier" ::: "memory")
#define LGKM0 do { asm volatile("s_waitcnt lgkmcnt(0)" ::: "memory");          \
                   __builtin_amdgcn_sched_barrier(0); } while (0)

#define LDA(base)                                                              \
    _Pragma("unroll") for (int mi2 = 0; mi2 < 4; ++mi2)                        \
    _Pragma("unroll") for (int ks = 0; ks < 2; ++ks)                           \
        afr[mi2][ks] = __builtin_bit_cast(bf16x8,                              \
            *(const i32x4*)&lds[(base) + ((ar0 + mi2 * 1024 + ks * 32) ^ axr)]);

#define LDB(dst, base)                                                         \
    _Pragma("unroll") for (int ni2 = 0; ni2 < 2; ++ni2)                        \
    _Pragma("unroll") for (int ks = 0; ks < 2; ++ks)                           \
        dst[ni2][ks] = __builtin_bit_cast(bf16x8,                              \
            *(const i32x4*)&lds[(base) + ((br0 + ni2 * 1024 + ks * 32) ^ axr)]);

#define MFMA_Q(mb, nb, bfrag)                                                  \
    __builtin_amdgcn_s_setprio(1);                                             \
    _Pragma("unroll") for (int mi2 = 0; mi2 < 4; ++mi2)                        \
    _Pragma("unroll") for (int ni2 = 0; ni2 < 2; ++ni2)                        \
    _Pragma("unroll") for (int ks = 0; ks < 2; ++ks)                           \
        acc[(mb) + mi2][(nb) + ni2] = __builtin_amdgcn_mfma_f32_16x16x32_bf16( \
            afr[mi2][ks], bfrag[ni2][ks], acc[(mb) + mi2][(nb) + ni2], 0, 0, 0); \
    __builtin_amdgcn_s_setprio(0)

    f32x4 acc[8][4];
#pragma unroll
    for (int i = 0; i < 8; ++i)
#pragma unroll
        for (int j = 0; j < 4; ++j) acc[i][j] = (f32x4)0.0f;

    bf16x8 afr[4][2], b0f[2][2], b1f[2][2];

    const int nt = K >> 6;

    STAGE_A(0, 0, 0); STAGE_B(0, 0, 0);
    STAGE_A(0, 1, 0); STAGE_B(0, 1, 0);
    STAGE_A(1, 0, 1); STAGE_B(1, 0, 1);

    for (int T = 0; T < nt; ++T) {
        const int cur = T & 1, nxt = cur ^ 1;
        const int ab = (cur << 1) * 8192;
        const int bb = 32768 + (cur << 1) * 8192;

        if (T + 1 < nt) asm volatile("s_waitcnt vmcnt(4)" ::: "memory");
        else            asm volatile("s_waitcnt vmcnt(0)" ::: "memory");
        SBAR;
        LDA(ab); LDB(b0f, bb);
        if (T + 1 < nt) STAGE_B(nxt, 1, T + 1);
        SBAR; LGKM0;
        MFMA_Q(0, 0, b0f);
        SBAR;
        LDB(b1f, bb + 8192);
        if (T + 1 < nt) STAGE_A(nxt, 1, T + 1);
        SBAR; LGKM0;
        MFMA_Q(0, 2, b1f);
        SBAR;
        LDA(ab + 8192);
        if (T + 2 < nt) STAGE_A(cur, 0, T + 2);
        SBAR; LGKM0;
        MFMA_Q(4, 0, b0f);
        SBAR;
        if (T + 2 < nt) STAGE_B(cur, 0, T + 2);
        SBAR; LGKM0;
        MFMA_Q(4, 2, b1f);
        SBAR;
    }

    // epilogue: fp32 direct + bf16 via LDS two-pass
    const int cr0 = m0 + wr * 128 + ((lane >> 4) << 2);
    const int cc0 = n0 + wc * 64 + (lane & 15);
    float* Cg = C32 + (size_t)z * sC;
#pragma unroll
    for (int mi = 0; mi < 8; ++mi)
#pragma unroll
        for (int ni = 0; ni < 4; ++ni)
#pragma unroll
            for (int j = 0; j < 4; ++j)
                Cg[(size_t)(cr0 + mi * 16 + j) * N + cc0 + ni * 16] = acc[mi][ni][j];

    u16* sE = lds;                         // [128][264] u16
    u16* Cb = C16 + (size_t)z * sC;
    const int wrow0 = ((lane >> 4) << 2);
    const int wcol0 = wc * 64 + (lane & 15);
    const int rr = tid >> 2;
    const int c0 = (tid & 3) * 8;
    __syncthreads();
#pragma unroll
    for (int p = 0; p < 2; ++p) {
        if (wr == p) {
#pragma unroll
            for (int mi = 0; mi < 8; ++mi)
#pragma unroll
                for (int ni = 0; ni < 4; ++ni)
#pragma unroll
                    for (int j = 0; j < 4; ++j)
                        sE[(wrow0 + mi * 16 + j) * 264 + wcol0 + ni * 16] =
                            f2b(acc[mi][ni][j]);
        }
        __syncthreads();
#pragma unroll
        for (int i = 0; i < 8; ++i) {
            i32x4 vv = *(const i32x4*)&sE[rr * 264 + c0 + i * 32];
            *(i32x4*)&Cb[(size_t)(m0 + p * 128 + rr) * N + n0 + c0 + i * 32] = vv;
        }
        if (p == 0) __syncthreads();
    }
#undef GLL16
#undef STAGE_A
#undef STAGE_B
#undef LDA
#undef LDB
#undef MFMA_Q
}

// ===========================================================================
// gemm_bw: BMx128 TN GEMM, 256 threads / 4 waves (2M x 2N), per-wave
// (BM/2)x64, BK=32, 3-buffer LDS ring, one phase per K-tile.
// LDS: 3 x { A[BM][32] | B[128][32] } = 3*(BM+128)*64 B (72 KB / 48 KB).
// Swizzle: gemm128's proven [*][32] pattern — stage granule cl = g^((g>>3)&3),
// read elem XOR exr = ((lane>>1)&3)<<3 (row bits 1-2 from lane&15 only;
// wr/wc/mi/ni row terms are 0 mod 8).
// Phase T (buf b0 = T%3): {vmcnt(G); bar} read A frags(AMI) + B frags(4)
// from b0 | STAGE(T+2)->b2 | lgkm0 | prio AMIx4 MFMA. Rotate (b0,b1,b2).
//  G = GLLs per stage = BM/64 + 2 (6 for BM=256, 4 for BM=128).
//  vmcnt proof: stages issue in tile order; at boundary T outstanding
//  <= {stage(T),stage(T+1)}; vmcnt(G) leaves stage(T+1) -> stage(T) landed.
//  Tail (T=nt-1): vmcnt(0).
//  Ring safety: stage(T+2) targets buf[(T+2)%3] = buf[(T-1)%3], whose last
//  reads retired at lgkm0(T-1) before the barrier at T that precedes the
//  stage issue. In-flight stage(T+1) targets the third buffer. Disjoint.
//  K accumulated in ascending 32-chunks — bitwise-identical to R6.
// EPI: 1 = exp(acc+bias)->bf16 LDS-coalesced (proj; z==2 -> Calt);
//      2 = fp32 direct (out).
// ===========================================================================
template<int EPI, int BM>
__global__ __launch_bounds__(256, 2) void gemm_bw(
    const u16* __restrict__ Ap, const u16* __restrict__ Bp,
    float* __restrict__ C32, u16* __restrict__ C16, u16* __restrict__ Calt,
    const float* __restrict__ bias,
    int N, int K, long long sA, long long sB, long long sC)
{
    constexpr int AMI = BM / 32;            // A frags / acc rows (8 or 4)
    constexpr int ALD = BM / 64;            // A GLLs per stage (4 or 2)
    constexpr int ASZ = BM * 32;            // A buffer elems
    constexpr int BUF = ASZ + 4096;         // ring stride elems
    __shared__ __align__(16) u16 lds[3 * BUF];

    const int tid  = threadIdx.x;
    const int lane = tid & 63;
    const int w    = tid >> 6;
    const int wr   = w >> 1, wc = w & 1;    // 2M x 2N waves

    const int gx  = gridDim.x;
    const int tot = gx * gridDim.y;
    const int lin = blockIdx.y * gx + blockIdx.x;
    const int vlin = (lin & 7) * (tot >> 3) + (lin >> 3);
    const int bx = vlin % gx, by = vlin / gx;
    const int m0 = by * BM, n0 = bx * 128;
    const int z  = blockIdx.z;

    const u16* Ag = Ap + (size_t)z * sA;
    const u16* Bg = Bp + (size_t)z * sB;

    // staging: granule g = ld*256 + tid; cl = g ^ ((g>>3)&3) = ld*256 + cltid
    const int cltid = tid ^ ((tid >> 3) & 3);
    const int crow  = cltid >> 2;           // row within 64-row chunk
    const int ce    = (cltid & 3) * 8;      // col element 0/8/16/24

    // frag reads
    const int exr = ((lane >> 1) & 3) << 3;
    const int ar0 = (wr * (BM / 2) + (lane & 15)) * 32 + (lane >> 4) * 8;
    const int br0 = (wc * 64 + (lane & 15)) * 32 + (lane >> 4) * 8;

#define GLLW(gsrc, ldsoff)                                                     \
    __builtin_amdgcn_global_load_lds(                                          \
        (__attribute__((address_space(1))) void*)(uintptr_t)(gsrc),            \
        (__attribute__((address_space(3))) void*)&lds[ldsoff], 16, 0, 0)

#define STAGE(buf, T)                                                          \
    do {                                                                       \
        _Pragma("unroll") for (int ld = 0; ld < ALD; ++ld)                     \
            GLLW(Ag + (size_t)(m0 + ld * 64 + crow) * K + (T) * 32 + ce,       \
                 (buf) + ld * 2048 + tid * 8);                                 \
        _Pragma("unroll") for (int ld = 0; ld < 2; ++ld)                       \
            GLLW(Bg + (size_t)(n0 + ld * 64 + crow) * K + (T) * 32 + ce,       \
                 (buf) + ASZ + ld * 2048 + tid * 8);                           \
    } while (0)

#define LGKM0B do { asm volatile("s_waitcnt lgkmcnt(0)" ::: "memory");         \
                    __builtin_amdgcn_sched_barrier(0); } while (0)

    f32x4 acc[AMI][4];
#pragma unroll
    for (int i = 0; i < AMI; ++i)
#pragma unroll
        for (int j = 0; j < 4; ++j) acc[i][j] = (f32x4)0.0f;

    bf16x8 afr[AMI], bfr[4];

    const int nt = K >> 5;

    int b0 = 0, b1 = BUF, b2 = 2 * BUF;
    STAGE(b0, 0); STAGE(b1, 1);

    for (int T = 0; T < nt; ++T) {
        if (T + 1 < nt) {
            if constexpr (BM == 256) asm volatile("s_waitcnt vmcnt(6)" ::: "memory");
            else                     asm volatile("s_waitcnt vmcnt(4)" ::: "memory");
        } else {
            asm volatile("s_waitcnt vmcnt(0)" ::: "memory");
        }
        asm volatile("s_barrier" ::: "memory");
#pragma unroll
        for (int mi = 0; mi < AMI; ++mi)
            afr[mi] = __builtin_bit_cast(bf16x8,
                *(const i32x4*)&lds[b0 + ((ar0 + mi * 512) ^ exr)]);
#pragma unroll
        for (int ni = 0; ni < 4; ++ni)
            bfr[ni] = __builtin_bit_cast(bf16x8,
                *(const i32x4*)&lds[b0 + ASZ + ((br0 + ni * 512) ^ exr)]);
        if (T + 2 < nt) STAGE(b2, T + 2);
        LGKM0B;
        __builtin_amdgcn_s_setprio(1);
#pragma unroll
        for (int mi = 0; mi < AMI; ++mi)
#pragma unroll
            for (int ni = 0; ni < 4; ++ni)
                acc[mi][ni] = __builtin_amdgcn_mfma_f32_16x16x32_bf16(
                    afr[mi], bfr[ni], acc[mi][ni], 0, 0, 0);
        __builtin_amdgcn_s_setprio(0);
        int tmp = b0; b0 = b1; b1 = b2; b2 = tmp;
    }

    // ---- epilogue ----
    // C row = m0 + wr*(BM/2) + mi*16 + (lane>>4)*4 + j
    // C col = n0 + wc*64 + ni*16 + (lane&15)
    if constexpr (EPI == 1) {                  // proj: exp+bias -> bf16, coalesced
        u16* sE = lds;                         // [BM][136] u16 (fits in 3*BUF)
        u16* Cb = (z == 2) ? Calt : (C16 + (size_t)z * sC);
        const int colb = wc * 64 + (lane & 15);
        float bv[4];
#pragma unroll
        for (int ni = 0; ni < 4; ++ni)
            bv[ni] = bias[(size_t)z * 1024 + n0 + colb + ni * 16];
        const int wrow0 = wr * (BM / 2) + ((lane >> 4) << 2);
        __syncthreads();                       // loop drained: vmcnt(0)+lgkm0 done
#pragma unroll
        for (int mi = 0; mi < AMI; ++mi)
#pragma unroll
            for (int ni = 0; ni < 4; ++ni)
#pragma unroll
                for (int j = 0; j < 4; ++j)
                    sE[(wrow0 + mi * 16 + j) * 136 + colb + ni * 16] =
                        f2b(__expf(acc[mi][ni][j] + bv[ni]));
        __syncthreads();
        const int rr = tid >> 2, c0 = (tid & 3) * 8;
#pragma unroll
        for (int rb = 0; rb < BM / 64; ++rb) {
            int row = rb * 64 + rr;
#pragma unroll
            for (int i = 0; i < 4; ++i) {
                i32x4 vv = *(const i32x4*)&sE[row * 136 + c0 + i * 32];
                *(i32x4*)&Cb[(size_t)(m0 + row) * N + n0 + c0 + i * 32] = vv;
            }
        }
    } else {                                   // out: fp32 direct
        float* Cg = C32 + (size_t)z * sC;
        const int cr0 = m0 + wr * (BM / 2) + ((lane >> 4) << 2);
        const int cc0 = n0 + wc * 64 + (lane & 15);
#pragma unroll
        for (int mi = 0; mi < AMI; ++mi)
#pragma unroll
            for (int ni = 0; ni < 4; ++ni)
#pragma unroll
                for (int j = 0; j < 4; ++j)
                    Cg[(size_t)(cr0 + mi * 16 + j) * N + cc0 + ni * 16] =
                        acc[mi][ni][j];
    }
#undef GLLW
#undef STAGE
#undef LGKM0B
}

// ---- fused: row softmax (qE) + column partials (kE, vE) --------------------
__global__ __launch_bounds__(256) void sm_partials(
    u16* __restrict__ qE, const u16* __restrict__ kE, const u16* __restrict__ vE,
    float* __restrict__ kpart, float* __restrict__ vpart)
{
    int bid = blockIdx.x, t = threadIdx.x;
    if (bid < 8192) {                          // row softmax over D=1024
        u16* p = qE + (size_t)bid * 1024;
        ushort4 v = *(ushort4*)&p[t * 4];
        float e0 = b2f(v.x), e1 = b2f(v.y), e2 = b2f(v.z), e3 = b2f(v.w);
        float s = (e0 + e1) + (e2 + e3);
#pragma unroll
        for (int off = 32; off; off >>= 1) s += __shfl_down(s, off);
        __shared__ float red[4];
        if ((t & 63) == 0) red[t >> 6] = s;
        __syncthreads();
        float inv = 1.0f / ((red[0] + red[1]) + (red[2] + red[3]));
        ushort4 o;
        o.x = f2b(e0 * inv); o.y = f2b(e1 * inv);
        o.z = f2b(e2 * inv); o.w = f2b(e3 * inv);
        *(ushort4*)&p[t * 4] = o;
    } else {                                   // column partials, 128-row chunks
        int j = bid - 8192;
        const u16* d; float* part;
        if (j < 64) { d = kE; part = kpart; } else { d = vE; part = vpart; j -= 64; }
        int b = j >> 4, c = j & 15;
        const u16* base = d + ((size_t)b * 2048 + c * 128) * 1024 + t * 4;
        float a0 = 0, a1 = 0, a2 = 0, a3 = 0;
        for (int s = 0; s < 128; ++s) {
            ushort4 v = *(const ushort4*)(base + (size_t)s * 1024);
            a0 += b2f(v.x); a1 += b2f(v.y); a2 += b2f(v.z); a3 += b2f(v.w);
        }
        *(float4*)(part + ((size_t)(b * 16 + c)) * 1024 + t * 4) = make_float4(a0, a1, a2, a3);
    }
}

// ---- fused: reduce partials -> kinv, vinv ---------------------------------
__global__ __launch_bounds__(256) void col_reduce2(
    const float* __restrict__ kpart, const float* __restrict__ vpart,
    float* __restrict__ kinv, float* __restrict__ vinv)
{
    int bid = blockIdx.x;
    const float* part; float* inv; float mult;
    if (bid < 16) { part = kpart; inv = kinv; mult = 0.03125f; }
    else          { part = vpart; inv = vinv; mult = 1.0f; bid -= 16; }
    int idx = bid * 256 + threadIdx.x;         // 0..4095 over (b,e)
    int b = idx >> 10, e = idx & 1023;
    float s = 0;
    for (int c = 0; c < 16; ++c) s += part[((size_t)(b * 16 + c)) * 1024 + e];
    inv[idx] = mult / s;
}

// ---- fused: kp in-place col-norm + vp normalize+transpose ------------------
__global__ __launch_bounds__(256) void norm_all(
    u16* __restrict__ kE, const float* __restrict__ kinv,
    const u16* __restrict__ vE, const float* __restrict__ vinv,
    u16* __restrict__ vpT)
{
    int bid = blockIdx.x, t = threadIdx.x;
    if (bid < 8192) {                          // col_norm on kE
        int b = bid >> 11, s = bid & 2047;
        u16* p = kE + ((size_t)b * 2048 + s) * 1024 + t * 4;
        float4 iv = *(const float4*)(kinv + b * 1024 + t * 4);
        ushort4 v = *(ushort4*)p;
        v.x = f2b(b2f(v.x) * iv.x); v.y = f2b(b2f(v.y) * iv.y);
        v.z = f2b(b2f(v.z) * iv.z); v.w = f2b(b2f(v.w) * iv.w);
        *(ushort4*)p = v;
    } else {                                   // transpose+norm vE -> vpT
        __shared__ __align__(16) u16 tile[64][68];
        int j = bid - 8192;
        int b = j >> 9, y = (j >> 5) & 15, x = j & 31;
        int s0 = x * 64, e0 = y * 64;
        int lr = t >> 4, lc = (t & 15) * 4;
#pragma unroll
        for (int i = 0; i < 4; ++i) {
            int sr = i * 16 + lr;
            ushort4 v = *(const ushort4*)(vE + ((size_t)b * 2048 + s0 + sr) * 1024 + e0 + lc);
            tile[sr][lc] = v.x; tile[sr][lc + 1] = v.y;
            tile[sr][lc + 2] = v.z; tile[sr][lc + 3] = v.w;
        }
        __syncthreads();
#pragma unroll
        for (int i = 0; i < 4; ++i) {
            int er = i * 16 + lr;
            float iv = vinv[b * 1024 + e0 + er];
            ushort4 v;
            v.x = f2b(b2f(tile[lc + 0][er]) * iv);
            v.y = f2b(b2f(tile[lc + 1][er]) * iv);
            v.z = f2b(b2f(tile[lc + 2][er]) * iv);
            v.w = f2b(b2f(tile[lc + 3][er]) * iv);
            *(ushort4*)(vpT + ((size_t)b * 1024 + e0 + er) * 2048 + s0 + lc) = v;
        }
    }
}

extern "C" void kernel_launch(void* const* d_in, const int* in_sizes, int n_in,
                              void* d_out, int out_size, void* d_ws, size_t ws_size,
                              hipStream_t stream)
{
    const float* q  = (const float*)d_in[0];
    const float* k  = (const float*)d_in[1];
    const float* v  = (const float*)d_in[2];
    const float* Wq = (const float*)d_in[3];
    const float* bq = (const float*)d_in[4];
    const float* Wk = (const float*)d_in[5];
    const float* bk = (const float*)d_in[6];
    const float* Wv = (const float*)d_in[7];
    const float* bv = (const float*)d_in[8];

    float* out  = (float*)d_out;          // [4,2048,1024] fp32
    float* attn = out + 8388608;          // [4,2048,2048] fp32

    u16* wsU = (u16*)d_ws;
    u16* qE   = wsU;                      // R0: exp'd q logits -> qp
    u16* kE   = wsU + 8388608;            // R1: exp'd k logits -> kp
    u16* Wb   = wsU + 16777216;           // R2: Wqb|Wkb|Wvb (stride 1M)
    u16* qb   = wsU + 25165824;           // R3: q bf16 (dead after proj)
    u16* kb   = wsU + 33554432;           // R4: k bf16 (dead after proj)
    u16* vb   = wsU + 41943040;           // R4+8.4M: v bf16 (dead after proj)
    u16* vpT  = wsU + 25165824;           // R3 after proj: vpT [4,1024,2048]
    u16* attnB = wsU + 33554432;          // R4 after proj: attn bf16
    u16* vE   = (u16*)attn;               // d_out attn region as scratch

    float* tail  = (float*)(wsU + 50331648);
    float* kpart = tail;                  // [4,16,1024]
    float* vpart = tail + 65536;
    float* kinv  = tail + 131072;         // [4,1024]
    float* vinv  = tail + 135168;
    float* biasCat = tail + 139264;       // [3,1024] bq|bk|bv

    const long long SD = 2048LL * 1024, SS = 2048LL * 2048, DS = 1024LL * 2048;

    // ---- 1: convert inputs + weights to bf16, gather biases ----
    cvt_all<<<dim3(27649), dim3(256), 0, stream>>>(
        (const float4*)q, (const float4*)k, (const float4*)v,
        (const float4*)Wq, (const float4*)Wk, (const float4*)Wv,
        bq, bk, bv,
        (ushort4*)qb, (ushort4*)kb, (ushort4*)vb, (ushort4*)Wb, biasCat);

    // ---- 2: batched projections (gemm_bw BM=256): z=0/1/2 -> qE, kE, vE ----
    gemm_bw<1, 256><<<dim3(8, 32, 3), dim3(256), 0, stream>>>(
        qb, Wb, nullptr, qE, vE, biasCat,
        1024, 1024, 8388608LL, 1048576LL, 8388608LL);

    // ---- 3: row softmax (qE) + col partials (kE, vE) ----
    sm_partials<<<dim3(8320), dim3(256), 0, stream>>>(qE, kE, vE, kpart, vpart);

    // ---- 4: reduce -> kinv (x 1/32), vinv ----
    col_reduce2<<<dim3(32), dim3(256), 0, stream>>>(kpart, vpart, kinv, vinv);

    // ---- 5: kp col-norm in place + vp normalize+transpose -> vpT ----
    norm_all<<<dim3(10240), dim3(256), 0, stream>>>(kE, kinv, vE, vinv, vpT);

    // ---- 6: attn = qp @ kp^T -> fp32 d_out + bf16 ws copy (256x256) ----
    gemm256_attn<<<dim3(8, 8, 4), dim3(512), 0, stream>>>(
        qE, kE, attn, attnB, 2048, 1024, SD, SD, SS);

    // ---- 7: out = attnB @ vpT^T -> fp32 d_out (gemm_bw BM=128) ----
    gemm_bw<2, 128><<<dim3(8, 16, 4), dim3(256), 0, stream>>>(
        attnB, vpT, out, nullptr, nullptr, nullptr, 1024, 2048, SS, DS, SD);
}